// Round 4
// baseline (408.805 us; speedup 1.0000x reference)
//
#include <hip/hip_runtime.h>
#include <hip/hip_bf16.h>

// B=2, S=128, H=12, DH=64, HID=768
// scores(b,h,i,j) = dot64(q+ra, k+rb)/8 + mask ; t = h*16384+i*128+j ; r=t/12, c=t%12
// ra = ip[r, 64c+d], rb = ip[r, 768+64c+d], ip = inference_path @ Wip (bf16 MFMA, never materialized)

typedef __attribute__((ext_vector_type(8))) __bf16 bf16x8;
typedef __attribute__((ext_vector_type(16))) float f32x16;
typedef __attribute__((ext_vector_type(4))) float f32x4;
typedef __attribute__((ext_vector_type(4))) unsigned int u32x4;

// ws layout (total 7,208,960 B — proven footprint)
#define QKV_OFF   0u         // [256][2368] f32 : q|k|v|pv
#define ARENA_OFF 2424832u   // 2304 B-frags x 1KB bf16 (Wip), frag = n32*48 + k16
#define SC_OFF    4784128u   // [2][12][128][128] f32
#define CTX_OFF   6356992u   // [256][832] f32

// ---------------- prep: Wip [768][1536] f32 -> bf16 B-frags ----------------
// frag f = n32*48 + k16 ; lane l: col = n32*32+(l&31), k = k16*16+(l>>5)*8+j
__global__ __launch_bounds__(256)
void prep_kernel(const float* __restrict__ Wip, __bf16* __restrict__ arena) {
  const int l = threadIdx.x & 63;
  const int f = blockIdx.x * 4 + (threadIdx.x >> 6);   // 0..2303
  const int n32 = f / 48, k16 = f - n32 * 48;
  const float* src = Wip + (size_t)(k16 * 16 + (l >> 5) * 8) * 1536 + n32 * 32 + (l & 31);
  union { __bf16 h[8]; uint4 u; } pk;
#pragma unroll
  for (int j = 0; j < 8; j++) pk.h[j] = (__bf16)src[(size_t)j * 1536];
  ((uint4*)arena)[(size_t)f * 64 + l] = pk.u;
}

// ---------------- proj: wave-block MFMA GEMM, full K, direct stores ----------------
// grid (74 n32-tiles, 8 m32-tiles) x 64 thr.
__global__ __launch_bounds__(64)
void proj_kernel(const float* __restrict__ hs,
                 const float* __restrict__ Wq, const float* __restrict__ bq,
                 const float* __restrict__ Wk, const float* __restrict__ bk,
                 const float* __restrict__ Wv, const float* __restrict__ bv,
                 const float* __restrict__ Wpv, const float* __restrict__ bpv,
                 float* __restrict__ qkv) {
  const int n0 = blockIdx.x * 32;   // combined col space [q|k|v|pv] = 2368
  const int m0 = blockIdx.y * 32;
  const float* W; const float* bias; int noff, ldw;
  if (n0 < 768)       { W = Wq;  bias = bq;  noff = n0;        ldw = 768; }
  else if (n0 < 1536) { W = Wk;  bias = bk;  noff = n0 - 768;  ldw = 768; }
  else if (n0 < 2304) { W = Wv;  bias = bv;  noff = n0 - 1536; ldw = 768; }
  else                { W = Wpv; bias = bpv; noff = n0 - 2304; ldw = 64;  }
  const int l = threadIdx.x;
  const int rsel = l & 31, ksel = l >> 5;
  f32x16 acc;
#pragma unroll
  for (int z = 0; z < 16; z++) acc[z] = 0.f;

#pragma unroll 4
  for (int k16 = 0; k16 < 48; k16++) {
    const float* ap = hs + (size_t)(m0 + rsel) * 768 + k16 * 16 + ksel * 8;
    float4 a0 = *(const float4*)ap;
    float4 a1 = *(const float4*)(ap + 4);
    union { __bf16 h[8]; bf16x8 v; } pa;
    pa.h[0] = (__bf16)a0.x; pa.h[1] = (__bf16)a0.y; pa.h[2] = (__bf16)a0.z; pa.h[3] = (__bf16)a0.w;
    pa.h[4] = (__bf16)a1.x; pa.h[5] = (__bf16)a1.y; pa.h[6] = (__bf16)a1.z; pa.h[7] = (__bf16)a1.w;
    const float* bp = W + (size_t)(k16 * 16 + ksel * 8) * ldw + noff + rsel;
    union { __bf16 h[8]; bf16x8 v; } pb;
#pragma unroll
    for (int j = 0; j < 8; j++) pb.h[j] = (__bf16)bp[(size_t)j * ldw];
    acc = __builtin_amdgcn_mfma_f32_32x32x16_bf16(pa.v, pb.v, acc, 0, 0, 0);
  }
#pragma unroll
  for (int reg = 0; reg < 16; reg++) {
    int row = (reg & 3) + ((reg >> 2) << 3) + (ksel << 2);
    qkv[(size_t)(m0 + row) * 2368 + n0 + rsel] = acc[reg] + bias[noff + rsel];
  }
}

// ---------------- score: fused ip-GEMM + score reduction ----------------
// v5: 8 waves (v3 shape, padded A-LDS), B loads via inline-asm SRSRC
// buffer_load_dwordx4 into a 3-bank register ring, 3 slots deep (24 loads in
// flight), consumed behind counted s_waitcnt vmcnt(16) + sched_barrier(0).
// Compiler cannot see/drain these loads -> real prefetch distance (T4).
extern __shared__ char smem_raw[];

__global__ __launch_bounds__(512, 2)
void score_kernel(const float* __restrict__ infp,
                  const __bf16* __restrict__ arena,
                  const float* __restrict__ qkv,
                  float* __restrict__ scores) {
  char* Abase = smem_raw;                        // 96 frags * 1040 = 99840 B
  float* lds_sc = (float*)(smem_raw + 99840);    // 64*12 floats
  const int tid = threadIdx.x;
  const int lane = tid & 63;
  const int ml = lane & 31;
  const int kh = lane >> 5;
  const int wv = tid >> 6;        // 0..7
  const int wc = wv & 3;
  const int wd = wv >> 2;
  const int blk = blockIdx.x;
  const int b = blk >> 8;
  const int r0 = (blk & 255) << 6;

  for (int z = tid; z < 768; z += 512) lds_sc[z] = 0.f;

  // SRSRC descriptor over the 2,359,296-byte arena
  u32x4 srsrc;
  srsrc[0] = (unsigned)(unsigned long long)arena;
  srsrc[1] = (unsigned)(((unsigned long long)arena) >> 32);
  srsrc[2] = 2359296u;
  srsrc[3] = 0x00020000u;
  const unsigned rbo = 1179648u;                 // rb mirror: +1152 frags
  // byte voffset of slot frag base: n32=(2c+wd), frag=(n32*48+kc*4), +lane*16
  unsigned voff = (unsigned)((2 * wc + wd) * 49152 + lane * 16);
  int kpn = 0;                                   // kc the pointer targets

  u32x4 B0[8], B1[8], B2[8];
  bf16x8 Af[8];
  f32x16 acc_ra[2], acc_rb[2];

  auto issueB = [&](u32x4* bank) {
    asm volatile("buffer_load_dwordx4 %0, %1, %2, 0 offen offset:0"
                 : "=&v"(bank[0]) : "v"(voff), "s"(srsrc));
    asm volatile("buffer_load_dwordx4 %0, %1, %2, 0 offen offset:1024"
                 : "=&v"(bank[2]) : "v"(voff), "s"(srsrc));
    asm volatile("buffer_load_dwordx4 %0, %1, %2, 0 offen offset:2048"
                 : "=&v"(bank[4]) : "v"(voff), "s"(srsrc));
    asm volatile("buffer_load_dwordx4 %0, %1, %2, 0 offen offset:3072"
                 : "=&v"(bank[6]) : "v"(voff), "s"(srsrc));
    asm volatile("buffer_load_dwordx4 %0, %1, %2, %3 offen offset:0"
                 : "=&v"(bank[1]) : "v"(voff), "s"(srsrc), "s"(rbo));
    asm volatile("buffer_load_dwordx4 %0, %1, %2, %3 offen offset:1024"
                 : "=&v"(bank[3]) : "v"(voff), "s"(srsrc), "s"(rbo));
    asm volatile("buffer_load_dwordx4 %0, %1, %2, %3 offen offset:2048"
                 : "=&v"(bank[5]) : "v"(voff), "s"(srsrc), "s"(rbo));
    asm volatile("buffer_load_dwordx4 %0, %1, %2, %3 offen offset:3072"
                 : "=&v"(bank[7]) : "v"(voff), "s"(srsrc), "s"(rbo));
    if (kpn == 11) { voff += 348160u; kpn = 0; } else { voff += 4096u; kpn++; }
  };

  // prologue: 3 slots deep (24 loads) — lands during the HBM A-staging
  issueB(B0);
  issueB(B1);
  issueB(B2);

  // stage A: 64 rows x 768 f32 -> bf16 frag-ordered LDS (HBM read-once, nt)
  {
    const f32x4* A4 = (const f32x4*)(infp + (size_t)(b * 16384 + r0) * 768);
#pragma unroll
    for (int p = 0; p < 12; p++) {
      int idx = p * 512 + tid;
      int m = (int)(((unsigned)idx * 10923u) >> 20);   // idx/96
      int g = idx - m * 96;
      f32x4 v0 = __builtin_nontemporal_load(A4 + m * 192 + g * 2);
      f32x4 v1 = __builtin_nontemporal_load(A4 + m * 192 + g * 2 + 1);
      union { __bf16 h[8]; uint4 u; } pk;
      pk.h[0] = (__bf16)v0[0]; pk.h[1] = (__bf16)v0[1];
      pk.h[2] = (__bf16)v0[2]; pk.h[3] = (__bf16)v0[3];
      pk.h[4] = (__bf16)v1[0]; pk.h[5] = (__bf16)v1[1];
      pk.h[6] = (__bf16)v1[2]; pk.h[7] = (__bf16)v1[3];
      int F = (m >> 5) * 48 + (g >> 1);
      int slot = (m & 31) + ((g & 1) << 5);
      *(uint4*)(Abase + ((F * 65 + slot) << 4)) = pk.u;
    }
  }
  __syncthreads();

  const size_t lane_off = (size_t)(lane << 4);
  auto loadA = [&](int kcc) {
    const char* ab = Abase + lane_off + kcc * 4160;
#pragma unroll
    for (int mt = 0; mt < 2; mt++)
#pragma unroll
      for (int ks = 0; ks < 4; ks++)
        Af[mt * 4 + ks] = *(const bf16x8*)(ab + mt * 49920 + ks * 1040);
  };
  auto mfma_step = [&](const u32x4* Bb) {
#pragma unroll
    for (int ks = 0; ks < 4; ks++) {
      bf16x8 bra = __builtin_bit_cast(bf16x8, Bb[ks * 2]);
      bf16x8 brb = __builtin_bit_cast(bf16x8, Bb[ks * 2 + 1]);
#pragma unroll
      for (int mt = 0; mt < 2; mt++) {
        acc_ra[mt] = __builtin_amdgcn_mfma_f32_32x32x16_bf16(Af[mt * 4 + ks], bra, acc_ra[mt], 0, 0, 0);
        acc_rb[mt] = __builtin_amdgcn_mfma_f32_32x32x16_bf16(Af[mt * 4 + ks], brb, acc_rb[mt], 0, 0, 0);
      }
    }
  };
  auto epilogue = [&](int c) {
    int d = wd * 32 + ml;
#pragma unroll
    for (int mt = 0; mt < 2; mt++) {
      float qv[16], kv[16];
#pragma unroll
      for (int reg = 0; reg < 16; reg++) {
        int row = mt * 32 + (reg & 3) + ((reg >> 2) << 3) + (kh << 2);
        int t = 12 * (r0 + row) + c;
        int hh = t >> 14;
        int ii = (t >> 7) & 127;
        int jj = t & 127;
        qv[reg] = qkv[(size_t)((b << 7) + ii) * 2368 + (hh << 6) + d];
        kv[reg] = qkv[(size_t)((b << 7) + jj) * 2368 + 768 + (hh << 6) + d];
      }
#pragma unroll
      for (int reg = 0; reg < 16; reg++) {
        int row = mt * 32 + (reg & 3) + ((reg >> 2) << 3) + (kh << 2);
        float p = (qv[reg] + acc_ra[mt][reg]) * (kv[reg] + acc_rb[mt][reg]);
        p += __shfl_xor(p, 16);
        p += __shfl_xor(p, 8);
        p += __shfl_xor(p, 4);
        p += __shfl_xor(p, 2);
        p += __shfl_xor(p, 1);
        if (ml == 0) atomicAdd(&lds_sc[row * 12 + c], p);
      }
    }
#pragma unroll
    for (int mt = 0; mt < 2; mt++)
#pragma unroll
      for (int z = 0; z < 16; z++) { acc_ra[mt][z] = 0.f; acc_rb[mt][z] = 0.f; }
  };

#pragma unroll
  for (int mt = 0; mt < 2; mt++)
#pragma unroll
    for (int z = 0; z < 16; z++) { acc_ra[mt][z] = 0.f; acc_rb[mt][z] = 0.f; }

#define WAIT16 do { asm volatile("s_waitcnt vmcnt(16)" ::: "memory"); __builtin_amdgcn_sched_barrier(0); } while (0)
#define WAIT8  do { asm volatile("s_waitcnt vmcnt(8)"  ::: "memory"); __builtin_amdgcn_sched_barrier(0); } while (0)
#define WAIT0  do { asm volatile("s_waitcnt vmcnt(0)"  ::: "memory"); __builtin_amdgcn_sched_barrier(0); } while (0)

  // 36 slots; slot s consumes bank s%3 and issues slot s+3 into the same bank.
  // Steady state: 24 loads outstanding; vmcnt(16) == "slot s's 8 are done".
  int kc = 0, c = wc;
#pragma unroll 1
  for (int it = 0; it < 11; it++) {
    {
      loadA(kc); WAIT16; mfma_step(B0); issueB(B0);
      if (kc == 11) { epilogue(c); kc = 0; c += 4; } else kc++;
    }
    {
      loadA(kc); WAIT16; mfma_step(B1); issueB(B1);
      if (kc == 11) { epilogue(c); kc = 0; c += 4; } else kc++;
    }
    {
      loadA(kc); WAIT16; mfma_step(B2); issueB(B2);
      if (kc == 11) { epilogue(c); kc = 0; c += 4; } else kc++;
    }
  }
  // peeled tail: slots 33,34,35 (kc = 9,10,11 of c = wc+8) — no more issues
  loadA(kc); WAIT16; mfma_step(B0); kc++;
  loadA(kc); WAIT8;  mfma_step(B1); kc++;
  loadA(kc); WAIT0;  mfma_step(B2); epilogue(c);

#undef WAIT16
#undef WAIT8
#undef WAIT0

  __syncthreads();
  for (int z = tid; z < 768; z += 512) {
    int row = z / 12;
    int ccc = z - row * 12;
    int t = 12 * (r0 + row) + ccc;
    int hh = t >> 14;
    int ii = (t >> 7) & 127;
    int jj = t & 127;
    scores[(size_t)((b * 12 + hh) * 128 + ii) * 128 + jj] = lds_sc[z];
  }
}

// ---------------- attn: one (b,i) per block; softmax 13 rows + PV dots from qkv ----------------
__global__ __launch_bounds__(256)
void attn_kernel(const float* __restrict__ scores, const float* __restrict__ qkv,
                 const float* __restrict__ mask, const float* __restrict__ span,
                 float* __restrict__ ctx) {
  const int i = blockIdx.x;
  const int b = blockIdx.y;
  const int tid = threadIdx.x;
  const int l = tid & 63;
  const int wvi = tid >> 6;
  __shared__ float w[13][132];
  for (int r = wvi; r < 13; r += 4) {
    if (r < 12) {
      const float* sp = scores + (size_t)((b * 12 + r) * 128 + i) * 128;
      float s0 = sp[l] * 0.125f + mask[b * 128 + l];
      float s1 = sp[l + 64] * 0.125f + mask[b * 128 + l + 64];
      float mx = fmaxf(s0, s1);
#pragma unroll
      for (int o = 32; o; o >>= 1) mx = fmaxf(mx, __shfl_xor(mx, o));
      float e0 = __expf(s0 - mx), e1 = __expf(s1 - mx);
      float sm = e0 + e1;
#pragma unroll
      for (int o = 32; o; o >>= 1) sm += __shfl_xor(sm, o);
      float inv = 1.f / sm;
      w[r][l] = e0 * inv;
      w[r][l + 64] = e1 * inv;
    } else {
      const float* sp = span + (size_t)(b * 128 + i) * 128;
      w[12][l] = sp[l];
      w[12][l + 64] = sp[l + 64];
    }
  }
  __syncthreads();
  for (int o = tid; o < 832; o += 256) {
    int h = o >> 6, d = o & 63;
    const float* vp = qkv + (size_t)(b * 128) * 2368 + (h < 12 ? 1536 + h * 64 : 2304) + d;
    float acc = 0.f;
#pragma unroll 8
    for (int j = 0; j < 128; j++) acc += w[h][j] * vp[(size_t)j * 2368];
    ctx[(size_t)(b * 128 + i) * 832 + o] = acc;
  }
}

// ---------------- out: wave-block MFMA GEMM, full K, direct stores ----------------
// grid (24 n32, 8 m32) x 64 thr. ctx[256x832] @ Wmlp[832x768] + bmlp.
__global__ __launch_bounds__(64)
void out_kernel(const float* __restrict__ ctxb, const float* __restrict__ Wmlp,
                const float* __restrict__ bmlp, float* __restrict__ out) {
  const int n0 = blockIdx.x * 32;
  const int m0 = blockIdx.y * 32;
  const int l = threadIdx.x;
  const int rsel = l & 31, ksel = l >> 5;
  f32x16 acc;
#pragma unroll
  for (int z = 0; z < 16; z++) acc[z] = 0.f;

#pragma unroll 4
  for (int k16 = 0; k16 < 52; k16++) {
    const float* ap = ctxb + (size_t)(m0 + rsel) * 832 + k16 * 16 + ksel * 8;
    float4 a0 = *(const float4*)ap;
    float4 a1 = *(const float4*)(ap + 4);
    union { __bf16 h[8]; bf16x8 v; } pa;
    pa.h[0] = (__bf16)a0.x; pa.h[1] = (__bf16)a0.y; pa.h[2] = (__bf16)a0.z; pa.h[3] = (__bf16)a0.w;
    pa.h[4] = (__bf16)a1.x; pa.h[5] = (__bf16)a1.y; pa.h[6] = (__bf16)a1.z; pa.h[7] = (__bf16)a1.w;
    const float* bp = Wmlp + (size_t)(k16 * 16 + ksel * 8) * 768 + n0 + rsel;
    union { __bf16 h[8]; bf16x8 v; } pb;
#pragma unroll
    for (int j = 0; j < 8; j++) pb.h[j] = (__bf16)bp[(size_t)j * 768];
    acc = __builtin_amdgcn_mfma_f32_32x32x16_bf16(pa.v, pb.v, acc, 0, 0, 0);
  }
#pragma unroll
  for (int reg = 0; reg < 16; reg++) {
    int row = (reg & 3) + ((reg >> 2) << 3) + (ksel << 2);
    out[(size_t)(m0 + row) * 768 + n0 + rsel] = acc[reg] + bmlp[n0 + rsel];
  }
}

// ---------------- launch ----------------
extern "C" void kernel_launch(void* const* d_in, const int* in_sizes, int n_in,
                              void* d_out, int out_size, void* d_ws, size_t ws_size,
                              hipStream_t stream) {
  const float* hs   = (const float*)d_in[0];
  const float* mask = (const float*)d_in[1];
  const float* infp = (const float*)d_in[2];
  const float* span = (const float*)d_in[3];
  const float* Wq   = (const float*)d_in[4];
  const float* bq   = (const float*)d_in[5];
  const float* Wk   = (const float*)d_in[6];
  const float* bk   = (const float*)d_in[7];
  const float* Wv   = (const float*)d_in[8];
  const float* bv   = (const float*)d_in[9];
  const float* Wpv  = (const float*)d_in[10];
  const float* bpv  = (const float*)d_in[11];
  const float* Wip  = (const float*)d_in[12];
  const float* Wmlp = (const float*)d_in[13];
  const float* bmlp = (const float*)d_in[14];
  float* out = (float*)d_out;

  char* ws = (char*)d_ws;
  float*  qkv    = (float*)(ws + QKV_OFF);
  __bf16* arena  = (__bf16*)(ws + ARENA_OFF);
  float*  scores = (float*)(ws + SC_OFF);
  float*  ctx    = (float*)(ws + CTX_OFF);

  prep_kernel<<<dim3(576), 256, 0, stream>>>(Wip, arena);
  proj_kernel<<<dim3(74, 8), 64, 0, stream>>>(hs, Wq, bq, Wk, bk, Wv, bv, Wpv, bpv, qkv);
  score_kernel<<<dim3(512), 512, 102912, stream>>>(infp, arena, qkv, scores);
  attn_kernel<<<dim3(128, 2), 256, 0, stream>>>(scores, qkv, mask, span, ctx);
  out_kernel<<<dim3(24, 8), 64, 0, stream>>>(ctx, Wmlp, bmlp, out);
}

// Round 5
// 392.300 us; speedup vs baseline: 1.0421x; 1.0421x over previous
//
#include <hip/hip_runtime.h>
#include <hip/hip_bf16.h>

// B=2, S=128, H=12, DH=64, HID=768
// scores(b,h,i,j) = dot64(q+ra, k+rb)/8 + mask ; t = h*16384+i*128+j ; r=t/12, c=t%12
// ra = ip[r, 64c+d], rb = ip[r, 768+64c+d], ip = inference_path @ Wip (bf16 MFMA, never materialized)

typedef __attribute__((ext_vector_type(8))) __bf16 bf16x8;
typedef __attribute__((ext_vector_type(16))) float f32x16;
typedef __attribute__((ext_vector_type(4))) float f32x4;
typedef __attribute__((ext_vector_type(4))) unsigned int u32x4;

// ws layout (total 7,208,960 B — proven footprint)
#define QKV_OFF   0u         // [256][2368] f32 : q|k|v|pv
#define ARENA_OFF 2424832u   // 2304 B-frags x 1KB bf16 (Wip), frag = n32*48 + k16
#define SC_OFF    4784128u   // [2][12][128][128] f32
#define CTX_OFF   6356992u   // [256][832] f32

// ---------------- prep: Wip [768][1536] f32 -> bf16 B-frags ----------------
// frag f = n32*48 + k16 ; lane l: col = n32*32+(l&31), k = k16*16+(l>>5)*8+j
__global__ __launch_bounds__(256)
void prep_kernel(const float* __restrict__ Wip, __bf16* __restrict__ arena) {
  const int l = threadIdx.x & 63;
  const int f = blockIdx.x * 4 + (threadIdx.x >> 6);   // 0..2303
  const int n32 = f / 48, k16 = f - n32 * 48;
  const float* src = Wip + (size_t)(k16 * 16 + (l >> 5) * 8) * 1536 + n32 * 32 + (l & 31);
  union { __bf16 h[8]; uint4 u; } pk;
#pragma unroll
  for (int j = 0; j < 8; j++) pk.h[j] = (__bf16)src[(size_t)j * 1536];
  ((uint4*)arena)[(size_t)f * 64 + l] = pk.u;
}

// ---------------- proj: wave-block MFMA GEMM, 4-m-tile loop (W read once/k16) ----------------
// grid (74 n32-tiles, 2 m-supers) x 64 thr. W traffic /4 vs per-m-tile grid.
__global__ __launch_bounds__(64)
void proj_kernel(const float* __restrict__ hs,
                 const float* __restrict__ Wq, const float* __restrict__ bq,
                 const float* __restrict__ Wk, const float* __restrict__ bk,
                 const float* __restrict__ Wv, const float* __restrict__ bv,
                 const float* __restrict__ Wpv, const float* __restrict__ bpv,
                 float* __restrict__ qkv) {
  const int n0 = blockIdx.x * 32;   // combined col space [q|k|v|pv] = 2368
  const int msup = blockIdx.y * 128;
  const float* W; const float* bias; int noff, ldw;
  if (n0 < 768)       { W = Wq;  bias = bq;  noff = n0;        ldw = 768; }
  else if (n0 < 1536) { W = Wk;  bias = bk;  noff = n0 - 768;  ldw = 768; }
  else if (n0 < 2304) { W = Wv;  bias = bv;  noff = n0 - 1536; ldw = 768; }
  else                { W = Wpv; bias = bpv; noff = n0 - 2304; ldw = 64;  }
  const int l = threadIdx.x;
  const int rsel = l & 31, ksel = l >> 5;
  f32x16 acc[4];
#pragma unroll
  for (int mi = 0; mi < 4; mi++)
#pragma unroll
    for (int z = 0; z < 16; z++) acc[mi][z] = 0.f;

#pragma unroll 2
  for (int k16 = 0; k16 < 48; k16++) {
    const float* bp = W + (size_t)(k16 * 16 + ksel * 8) * ldw + noff + rsel;
    union { __bf16 h[8]; bf16x8 v; } pb;
#pragma unroll
    for (int j = 0; j < 8; j++) pb.h[j] = (__bf16)bp[(size_t)j * ldw];
#pragma unroll
    for (int mi = 0; mi < 4; mi++) {
      const float* ap = hs + (size_t)(msup + mi * 32 + rsel) * 768 + k16 * 16 + ksel * 8;
      float4 a0 = *(const float4*)ap;
      float4 a1 = *(const float4*)(ap + 4);
      union { __bf16 h[8]; bf16x8 v; } pa;
      pa.h[0] = (__bf16)a0.x; pa.h[1] = (__bf16)a0.y; pa.h[2] = (__bf16)a0.z; pa.h[3] = (__bf16)a0.w;
      pa.h[4] = (__bf16)a1.x; pa.h[5] = (__bf16)a1.y; pa.h[6] = (__bf16)a1.z; pa.h[7] = (__bf16)a1.w;
      acc[mi] = __builtin_amdgcn_mfma_f32_32x32x16_bf16(pa.v, pb.v, acc[mi], 0, 0, 0);
    }
  }
#pragma unroll
  for (int mi = 0; mi < 4; mi++)
#pragma unroll
    for (int reg = 0; reg < 16; reg++) {
      int row = msup + mi * 32 + (reg & 3) + ((reg >> 2) << 3) + (ksel << 2);
      qkv[(size_t)row * 2368 + n0 + rsel] = acc[mi][reg] + bias[noff + rsel];
    }
}

// ---------------- score: fused ip-GEMM + score reduction ----------------
// v6: 3-bank inline-asm ring (24 loads in flight, counted vmcnt(16)), with the
// prologue issues AFTER the staging barrier (R4's spill: banks live through
// the fully-unrolled staging transient under a 128-reg clamp -> scratch).
// launch_bounds(512,1): allocator cap 256 (HW forces <=256 for 8-wave blocks).
extern __shared__ char smem_raw[];

__global__ __launch_bounds__(512, 1)
void score_kernel(const float* __restrict__ infp,
                  const __bf16* __restrict__ arena,
                  const float* __restrict__ qkv,
                  float* __restrict__ scores) {
  char* Abase = smem_raw;                        // 96 frags * 1040 = 99840 B
  float* lds_sc = (float*)(smem_raw + 99840);    // 64*12 floats
  const int tid = threadIdx.x;
  const int lane = tid & 63;
  const int ml = lane & 31;
  const int kh = lane >> 5;
  const int wv = tid >> 6;        // 0..7
  const int wc = wv & 3;
  const int wd = wv >> 2;
  const int blk = blockIdx.x;
  const int b = blk >> 8;
  const int r0 = (blk & 255) << 6;

  for (int z = tid; z < 768; z += 512) lds_sc[z] = 0.f;

  // SRSRC descriptor over the 2,359,296-byte arena
  u32x4 srsrc;
  srsrc[0] = (unsigned)(unsigned long long)arena;
  srsrc[1] = (unsigned)(((unsigned long long)arena) >> 32);
  srsrc[2] = 2359296u;
  srsrc[3] = 0x00020000u;
  const unsigned rbo = 1179648u;                 // rb mirror: +1152 frags
  // byte voffset of slot frag base: n32=(2c+wd), frag=(n32*48+kc*4), +lane*16
  unsigned voff = (unsigned)((2 * wc + wd) * 49152 + lane * 16);
  int kpn = 0;                                   // kc the pointer targets

  u32x4 B0[8], B1[8], B2[8];
  bf16x8 Af[8];
  f32x16 acc_ra[2], acc_rb[2];

  auto issueB = [&](u32x4* bank) {
    asm volatile("buffer_load_dwordx4 %0, %1, %2, 0 offen offset:0"
                 : "=&v"(bank[0]) : "v"(voff), "s"(srsrc));
    asm volatile("buffer_load_dwordx4 %0, %1, %2, 0 offen offset:1024"
                 : "=&v"(bank[2]) : "v"(voff), "s"(srsrc));
    asm volatile("buffer_load_dwordx4 %0, %1, %2, 0 offen offset:2048"
                 : "=&v"(bank[4]) : "v"(voff), "s"(srsrc));
    asm volatile("buffer_load_dwordx4 %0, %1, %2, 0 offen offset:3072"
                 : "=&v"(bank[6]) : "v"(voff), "s"(srsrc));
    asm volatile("buffer_load_dwordx4 %0, %1, %2, %3 offen offset:0"
                 : "=&v"(bank[1]) : "v"(voff), "s"(srsrc), "s"(rbo));
    asm volatile("buffer_load_dwordx4 %0, %1, %2, %3 offen offset:1024"
                 : "=&v"(bank[3]) : "v"(voff), "s"(srsrc), "s"(rbo));
    asm volatile("buffer_load_dwordx4 %0, %1, %2, %3 offen offset:2048"
                 : "=&v"(bank[5]) : "v"(voff), "s"(srsrc), "s"(rbo));
    asm volatile("buffer_load_dwordx4 %0, %1, %2, %3 offen offset:3072"
                 : "=&v"(bank[7]) : "v"(voff), "s"(srsrc), "s"(rbo));
    if (kpn == 11) { voff += 348160u; kpn = 0; } else { voff += 4096u; kpn++; }
  };

  // stage A: 64 rows x 768 f32 -> bf16 frag-ordered LDS (HBM read-once, nt)
  {
    const f32x4* A4 = (const f32x4*)(infp + (size_t)(b * 16384 + r0) * 768);
#pragma unroll
    for (int p = 0; p < 12; p++) {
      int idx = p * 512 + tid;
      int m = (int)(((unsigned)idx * 10923u) >> 20);   // idx/96
      int g = idx - m * 96;
      f32x4 v0 = __builtin_nontemporal_load(A4 + m * 192 + g * 2);
      f32x4 v1 = __builtin_nontemporal_load(A4 + m * 192 + g * 2 + 1);
      union { __bf16 h[8]; uint4 u; } pk;
      pk.h[0] = (__bf16)v0[0]; pk.h[1] = (__bf16)v0[1];
      pk.h[2] = (__bf16)v0[2]; pk.h[3] = (__bf16)v0[3];
      pk.h[4] = (__bf16)v1[0]; pk.h[5] = (__bf16)v1[1];
      pk.h[6] = (__bf16)v1[2]; pk.h[7] = (__bf16)v1[3];
      int F = (m >> 5) * 48 + (g >> 1);
      int slot = (m & 31) + ((g & 1) << 5);
      *(uint4*)(Abase + ((F * 65 + slot) << 4)) = pk.u;
    }
  }
  __syncthreads();

  // prologue: 3 slots deep (24 loads) — issued only now, so banks are never
  // live across the staging transient (R4's spill source).
  issueB(B0);
  issueB(B1);
  issueB(B2);

  const size_t lane_off = (size_t)(lane << 4);
  auto loadA = [&](int kcc) {
    const char* ab = Abase + lane_off + kcc * 4160;
#pragma unroll
    for (int mt = 0; mt < 2; mt++)
#pragma unroll
      for (int ks = 0; ks < 4; ks++)
        Af[mt * 4 + ks] = *(const bf16x8*)(ab + mt * 49920 + ks * 1040);
  };
  auto mfma_step = [&](const u32x4* Bb) {
#pragma unroll
    for (int ks = 0; ks < 4; ks++) {
      bf16x8 bra = __builtin_bit_cast(bf16x8, Bb[ks * 2]);
      bf16x8 brb = __builtin_bit_cast(bf16x8, Bb[ks * 2 + 1]);
#pragma unroll
      for (int mt = 0; mt < 2; mt++) {
        acc_ra[mt] = __builtin_amdgcn_mfma_f32_32x32x16_bf16(Af[mt * 4 + ks], bra, acc_ra[mt], 0, 0, 0);
        acc_rb[mt] = __builtin_amdgcn_mfma_f32_32x32x16_bf16(Af[mt * 4 + ks], brb, acc_rb[mt], 0, 0, 0);
      }
    }
  };
  auto epilogue = [&](int c) {
    int d = wd * 32 + ml;
#pragma unroll
    for (int mt = 0; mt < 2; mt++) {
      float qv[16], kv[16];
#pragma unroll
      for (int reg = 0; reg < 16; reg++) {
        int row = mt * 32 + (reg & 3) + ((reg >> 2) << 3) + (kh << 2);
        int t = 12 * (r0 + row) + c;
        int hh = t >> 14;
        int ii = (t >> 7) & 127;
        int jj = t & 127;
        qv[reg] = qkv[(size_t)((b << 7) + ii) * 2368 + (hh << 6) + d];
        kv[reg] = qkv[(size_t)((b << 7) + jj) * 2368 + 768 + (hh << 6) + d];
      }
#pragma unroll
      for (int reg = 0; reg < 16; reg++) {
        int row = mt * 32 + (reg & 3) + ((reg >> 2) << 3) + (kh << 2);
        float p = (qv[reg] + acc_ra[mt][reg]) * (kv[reg] + acc_rb[mt][reg]);
        p += __shfl_xor(p, 16);
        p += __shfl_xor(p, 8);
        p += __shfl_xor(p, 4);
        p += __shfl_xor(p, 2);
        p += __shfl_xor(p, 1);
        if (ml == 0) atomicAdd(&lds_sc[row * 12 + c], p);
      }
    }
#pragma unroll
    for (int mt = 0; mt < 2; mt++)
#pragma unroll
      for (int z = 0; z < 16; z++) { acc_ra[mt][z] = 0.f; acc_rb[mt][z] = 0.f; }
  };

#pragma unroll
  for (int mt = 0; mt < 2; mt++)
#pragma unroll
    for (int z = 0; z < 16; z++) { acc_ra[mt][z] = 0.f; acc_rb[mt][z] = 0.f; }

#define WAIT16 do { asm volatile("s_waitcnt vmcnt(16)" ::: "memory"); __builtin_amdgcn_sched_barrier(0); } while (0)
#define WAIT8  do { asm volatile("s_waitcnt vmcnt(8)"  ::: "memory"); __builtin_amdgcn_sched_barrier(0); } while (0)
#define WAIT0  do { asm volatile("s_waitcnt vmcnt(0)"  ::: "memory"); __builtin_amdgcn_sched_barrier(0); } while (0)

  // 36 slots; slot s consumes bank s%3 and issues slot s+3 into the same bank.
  // Steady state: 24 loads outstanding; vmcnt(16) == "slot s's 8 are done".
  int kc = 0, c = wc;
#pragma unroll 1
  for (int it = 0; it < 11; it++) {
    {
      loadA(kc); WAIT16; mfma_step(B0); issueB(B0);
      if (kc == 11) { epilogue(c); kc = 0; c += 4; } else kc++;
    }
    {
      loadA(kc); WAIT16; mfma_step(B1); issueB(B1);
      if (kc == 11) { epilogue(c); kc = 0; c += 4; } else kc++;
    }
    {
      loadA(kc); WAIT16; mfma_step(B2); issueB(B2);
      if (kc == 11) { epilogue(c); kc = 0; c += 4; } else kc++;
    }
  }
  // peeled tail: slots 33,34,35 (kc = 9,10,11 of c = wc+8) — no more issues
  loadA(kc); WAIT16; mfma_step(B0); kc++;
  loadA(kc); WAIT8;  mfma_step(B1); kc++;
  loadA(kc); WAIT0;  mfma_step(B2); epilogue(c);

#undef WAIT16
#undef WAIT8
#undef WAIT0

  __syncthreads();
  for (int z = tid; z < 768; z += 512) {
    int row = z / 12;
    int ccc = z - row * 12;
    int t = 12 * (r0 + row) + ccc;
    int hh = t >> 14;
    int ii = (t >> 7) & 127;
    int jj = t & 127;
    scores[(size_t)((b * 12 + hh) * 128 + ii) * 128 + jj] = lds_sc[z];
  }
}

// ---------------- attn: one (b,i) per block; softmax 13 rows + PV dots from qkv ----------------
__global__ __launch_bounds__(256)
void attn_kernel(const float* __restrict__ scores, const float* __restrict__ qkv,
                 const float* __restrict__ mask, const float* __restrict__ span,
                 float* __restrict__ ctx) {
  const int i = blockIdx.x;
  const int b = blockIdx.y;
  const int tid = threadIdx.x;
  const int l = tid & 63;
  const int wvi = tid >> 6;
  __shared__ float w[13][132];
  for (int r = wvi; r < 13; r += 4) {
    if (r < 12) {
      const float* sp = scores + (size_t)((b * 12 + r) * 128 + i) * 128;
      float s0 = sp[l] * 0.125f + mask[b * 128 + l];
      float s1 = sp[l + 64] * 0.125f + mask[b * 128 + l + 64];
      float mx = fmaxf(s0, s1);
#pragma unroll
      for (int o = 32; o; o >>= 1) mx = fmaxf(mx, __shfl_xor(mx, o));
      float e0 = __expf(s0 - mx), e1 = __expf(s1 - mx);
      float sm = e0 + e1;
#pragma unroll
      for (int o = 32; o; o >>= 1) sm += __shfl_xor(sm, o);
      float inv = 1.f / sm;
      w[r][l] = e0 * inv;
      w[r][l + 64] = e1 * inv;
    } else {
      const float* sp = span + (size_t)(b * 128 + i) * 128;
      w[12][l] = sp[l];
      w[12][l + 64] = sp[l + 64];
    }
  }
  __syncthreads();
  for (int o = tid; o < 832; o += 256) {
    int h = o >> 6, d = o & 63;
    const float* vp = qkv + (size_t)(b * 128) * 2368 + (h < 12 ? 1536 + h * 64 : 2304) + d;
    float acc = 0.f;
#pragma unroll 8
    for (int j = 0; j < 128; j++) acc += w[h][j] * vp[(size_t)j * 2368];
    ctx[(size_t)(b * 128 + i) * 832 + o] = acc;
  }
}

// ---------------- out: wave-block MFMA GEMM, 4-m-tile loop (Wmlp read once/k16) ----------------
// grid (24 n32, 2 m-supers) x 64 thr. ctx[256x832] @ Wmlp[832x768] + bmlp.
__global__ __launch_bounds__(64)
void out_kernel(const float* __restrict__ ctxb, const float* __restrict__ Wmlp,
                const float* __restrict__ bmlp, float* __restrict__ out) {
  const int n0 = blockIdx.x * 32;
  const int msup = blockIdx.y * 128;
  const int l = threadIdx.x;
  const int rsel = l & 31, ksel = l >> 5;
  f32x16 acc[4];
#pragma unroll
  for (int mi = 0; mi < 4; mi++)
#pragma unroll
    for (int z = 0; z < 16; z++) acc[mi][z] = 0.f;

#pragma unroll 2
  for (int k16 = 0; k16 < 52; k16++) {
    const float* bp = Wmlp + (size_t)(k16 * 16 + ksel * 8) * 768 + n0 + rsel;
    union { __bf16 h[8]; bf16x8 v; } pb;
#pragma unroll
    for (int j = 0; j < 8; j++) pb.h[j] = (__bf16)bp[(size_t)j * 768];
#pragma unroll
    for (int mi = 0; mi < 4; mi++) {
      const float* ap = ctxb + (size_t)(msup + mi * 32 + rsel) * 832 + k16 * 16 + ksel * 8;
      float4 a0 = *(const float4*)ap;
      float4 a1 = *(const float4*)(ap + 4);
      union { __bf16 h[8]; bf16x8 v; } pa;
      pa.h[0] = (__bf16)a0.x; pa.h[1] = (__bf16)a0.y; pa.h[2] = (__bf16)a0.z; pa.h[3] = (__bf16)a0.w;
      pa.h[4] = (__bf16)a1.x; pa.h[5] = (__bf16)a1.y; pa.h[6] = (__bf16)a1.z; pa.h[7] = (__bf16)a1.w;
      acc[mi] = __builtin_amdgcn_mfma_f32_32x32x16_bf16(pa.v, pb.v, acc[mi], 0, 0, 0);
    }
  }
#pragma unroll
  for (int mi = 0; mi < 4; mi++)
#pragma unroll
    for (int reg = 0; reg < 16; reg++) {
      int row = msup + mi * 32 + (reg & 3) + ((reg >> 2) << 3) + (ksel << 2);
      out[(size_t)row * 768 + n0 + rsel] = acc[mi][reg] + bmlp[n0 + rsel];
    }
}

// ---------------- launch ----------------
extern "C" void kernel_launch(void* const* d_in, const int* in_sizes, int n_in,
                              void* d_out, int out_size, void* d_ws, size_t ws_size,
                              hipStream_t stream) {
  const float* hs   = (const float*)d_in[0];
  const float* mask = (const float*)d_in[1];
  const float* infp = (const float*)d_in[2];
  const float* span = (const float*)d_in[3];
  const float* Wq   = (const float*)d_in[4];
  const float* bq   = (const float*)d_in[5];
  const float* Wk   = (const float*)d_in[6];
  const float* bk   = (const float*)d_in[7];
  const float* Wv   = (const float*)d_in[8];
  const float* bv   = (const float*)d_in[9];
  const float* Wpv  = (const float*)d_in[10];
  const float* bpv  = (const float*)d_in[11];
  const float* Wip  = (const float*)d_in[12];
  const float* Wmlp = (const float*)d_in[13];
  const float* bmlp = (const float*)d_in[14];
  float* out = (float*)d_out;

  char* ws = (char*)d_ws;
  float*  qkv    = (float*)(ws + QKV_OFF);
  __bf16* arena  = (__bf16*)(ws + ARENA_OFF);
  float*  scores = (float*)(ws + SC_OFF);
  float*  ctx    = (float*)(ws + CTX_OFF);

  prep_kernel<<<dim3(576), 256, 0, stream>>>(Wip, arena);
  proj_kernel<<<dim3(74, 2), 64, 0, stream>>>(hs, Wq, bq, Wk, bk, Wv, bv, Wpv, bpv, qkv);
  score_kernel<<<dim3(512), 512, 102912, stream>>>(infp, arena, qkv, scores);
  attn_kernel<<<dim3(128, 2), 256, 0, stream>>>(scores, qkv, mask, span, ctx);
  out_kernel<<<dim3(24, 2), 64, 0, stream>>>(ctx, Wmlp, bmlp, out);
}

// Round 6
// 378.509 us; speedup vs baseline: 1.0800x; 1.0364x over previous
//
#include <hip/hip_runtime.h>
#include <hip/hip_bf16.h>

// B=2, S=128, H=12, DH=64, HID=768
// scores(b,h,i,j) = dot64(q+ra, k+rb)/8 + mask ; t = h*16384+i*128+j ; r=t/12, c=t%12
// ra = ip[r, 64c+d], rb = ip[r, 768+64c+d], ip = inference_path @ Wip (bf16 MFMA, never materialized)

typedef __attribute__((ext_vector_type(8))) __bf16 bf16x8;
typedef __attribute__((ext_vector_type(16))) float f32x16;
typedef __attribute__((ext_vector_type(4))) float f32x4;

// ws layout (total 7,208,960 B — proven footprint)
#define QKV_OFF   0u         // [256][2368] f32 : q|k|v|pv
#define ARENA_OFF 2424832u   // 2304 B-frags x 1KB bf16 (Wip), frag = n32*48 + k16
#define SC_OFF    4784128u   // [2][12][128][128] f32
#define CTX_OFF   6356992u   // [256][832] f32

// ---------------- fused prep+proj (independent work, one launch) ----------------
// blocks 0..575: prep — Wip [768][1536] f32 -> bf16 B-frags
// blocks 576..723: proj — 4 waves = 4 m-tiles of the wave-block MFMA GEMM
__global__ __launch_bounds__(256)
void prep_proj_kernel(const float* __restrict__ Wip, __bf16* __restrict__ arena,
                      const float* __restrict__ hs,
                      const float* __restrict__ Wq, const float* __restrict__ bq,
                      const float* __restrict__ Wk, const float* __restrict__ bk,
                      const float* __restrict__ Wv, const float* __restrict__ bv,
                      const float* __restrict__ Wpv, const float* __restrict__ bpv,
                      float* __restrict__ qkv) {
  if (blockIdx.x < 576) {
    // ---- prep: frag f = n32*48 + k16 ; lane l: col = n32*32+(l&31), k = k16*16+(l>>5)*8+j
    const int l = threadIdx.x & 63;
    const int f = blockIdx.x * 4 + (threadIdx.x >> 6);   // 0..2303
    const int n32 = f / 48, k16 = f - n32 * 48;
    const float* src = Wip + (size_t)(k16 * 16 + (l >> 5) * 8) * 1536 + n32 * 32 + (l & 31);
    union { __bf16 h[8]; uint4 u; } pk;
#pragma unroll
    for (int j = 0; j < 8; j++) pk.h[j] = (__bf16)src[(size_t)j * 1536];
    ((uint4*)arena)[(size_t)f * 64 + l] = pk.u;
    return;
  }
  // ---- proj: pblk -> (n-tile, m-quad); wave = m-tile within quad
  const int pblk = blockIdx.x - 576;                     // 0..147
  const int n0 = (pblk % 74) * 32;                       // combined col space 2368
  const int m0 = (pblk / 74) * 128 + (threadIdx.x >> 6) * 32;
  const float* W; const float* bias; int noff, ldw;
  if (n0 < 768)       { W = Wq;  bias = bq;  noff = n0;        ldw = 768; }
  else if (n0 < 1536) { W = Wk;  bias = bk;  noff = n0 - 768;  ldw = 768; }
  else if (n0 < 2304) { W = Wv;  bias = bv;  noff = n0 - 1536; ldw = 768; }
  else                { W = Wpv; bias = bpv; noff = n0 - 2304; ldw = 64;  }
  const int l = threadIdx.x & 63;
  const int rsel = l & 31, ksel = l >> 5;
  f32x16 acc;
#pragma unroll
  for (int z = 0; z < 16; z++) acc[z] = 0.f;

#pragma unroll 4
  for (int k16 = 0; k16 < 48; k16++) {
    const float* ap = hs + (size_t)(m0 + rsel) * 768 + k16 * 16 + ksel * 8;
    float4 a0 = *(const float4*)ap;
    float4 a1 = *(const float4*)(ap + 4);
    union { __bf16 h[8]; bf16x8 v; } pa;
    pa.h[0] = (__bf16)a0.x; pa.h[1] = (__bf16)a0.y; pa.h[2] = (__bf16)a0.z; pa.h[3] = (__bf16)a0.w;
    pa.h[4] = (__bf16)a1.x; pa.h[5] = (__bf16)a1.y; pa.h[6] = (__bf16)a1.z; pa.h[7] = (__bf16)a1.w;
    const float* bp = W + (size_t)(k16 * 16 + ksel * 8) * ldw + noff + rsel;
    union { __bf16 h[8]; bf16x8 v; } pb;
#pragma unroll
    for (int j = 0; j < 8; j++) pb.h[j] = (__bf16)bp[(size_t)j * ldw];
    acc = __builtin_amdgcn_mfma_f32_32x32x16_bf16(pa.v, pb.v, acc, 0, 0, 0);
  }
#pragma unroll
  for (int reg = 0; reg < 16; reg++) {
    int row = (reg & 3) + ((reg >> 2) << 3) + (ksel << 2);
    qkv[(size_t)(m0 + row) * 2368 + n0 + rsel] = acc[reg] + bias[noff + rsel];
  }
}

// ---------------- score: fused ip-GEMM + score reduction ----------------
// v7: c-half split pinned to XCD groups. blk%8 = XCD; XCD 0..3 -> c 0..5,
// XCD 4..7 -> c 6..11. Each XCD touches only 1.18 MB of arena -> L2-resident
// (theory: compute phase was B-supply-BW-bound from L3 due to L2 thrash by
// the staging stream). 12 waves = one c per wave (wd halves), 12 kc slots.
// Cost: infp staged twice (nt-hinted, L3-served). R2-proven compiler-scheduled
// 3-bank B loads — no inline asm, no spill.
extern __shared__ char smem_raw[];

__global__ __launch_bounds__(768, 1)
void score_kernel(const float* __restrict__ infp,
                  const __bf16* __restrict__ arena,
                  const float* __restrict__ qkv,
                  float* __restrict__ scores) {
  char* Abase = smem_raw;                        // 96 frags * 1040 = 99840 B
  float* lds_sc = (float*)(smem_raw + 99840);    // 64 rows * 6 c = 384 f32
  const int tid = threadIdx.x;
  const int lane = tid & 63;
  const int ml = lane & 31;
  const int kh = lane >> 5;
  const int wv = tid >> 6;        // 0..11
  const int wd = (wv >= 6) ? 1 : 0;
  const int cc = wv - 6 * wd;     // 0..5
  const int blk = blockIdx.x;     // 0..1023
  const int xcd = blk & 7;
  const int chalf = xcd >> 2;
  const int id = ((blk >> 3) << 2) + (xcd & 3);  // 0..511, bijective per chalf
  const int b = id >> 8;
  const int r0 = (id & 255) << 6;
  const int c = chalf * 6 + cc;
  const int n32 = 2 * c + wd;

  if (tid < 384) lds_sc[tid] = 0.f;

  // B stream: frag f = n32*48 + kc*4 + ks ; rb mirror +1152 frags (+73728 uint4)
  const uint4* bptr  = (const uint4*)arena + (size_t)(n32 * 48) * 64 + lane;
  const uint4* bptr2 = bptr + 73728;
  uint4 B0[8], B1[8], B2[8];
  bf16x8 Af[8];
  f32x16 acc_ra[2], acc_rb[2];

  auto loadB = [&](uint4* dst) {
#pragma unroll
    for (int ks = 0; ks < 4; ks++) {
      dst[ks * 2]     = bptr[ks * 64];           // ra
      dst[ks * 2 + 1] = bptr2[ks * 64];          // rb
    }
    bptr += 256; bptr2 += 256;                   // next kc
  };

  // prefetch kc=0,1 : overlaps the HBM/L3 A-staging
  loadB(B0);
  loadB(B1);

  // stage A: 64 rows x 768 f32 -> bf16 frag-ordered LDS (nt: keep out of L2)
  {
    const f32x4* A4 = (const f32x4*)(infp + (size_t)(b * 16384 + r0) * 768);
#pragma unroll
    for (int p = 0; p < 8; p++) {
      int idx = p * 768 + tid;                   // 0..6143
      int m = (int)(((unsigned)idx * 10923u) >> 20);   // idx/96
      int g = idx - m * 96;
      f32x4 v0 = __builtin_nontemporal_load(A4 + m * 192 + g * 2);
      f32x4 v1 = __builtin_nontemporal_load(A4 + m * 192 + g * 2 + 1);
      union { __bf16 h[8]; uint4 u; } pk;
      pk.h[0] = (__bf16)v0[0]; pk.h[1] = (__bf16)v0[1];
      pk.h[2] = (__bf16)v0[2]; pk.h[3] = (__bf16)v0[3];
      pk.h[4] = (__bf16)v1[0]; pk.h[5] = (__bf16)v1[1];
      pk.h[6] = (__bf16)v1[2]; pk.h[7] = (__bf16)v1[3];
      int F = (m >> 5) * 48 + (g >> 1);
      int slot = (m & 31) + ((g & 1) << 5);
      *(uint4*)(Abase + ((F * 65 + slot) << 4)) = pk.u;
    }
  }
  __syncthreads();

  const size_t lane_off = (size_t)(lane << 4);
  auto loadA = [&](int kcc) {
    const char* ab = Abase + lane_off + kcc * 4160;
#pragma unroll
    for (int mt = 0; mt < 2; mt++)
#pragma unroll
      for (int ks = 0; ks < 4; ks++)
        Af[mt * 4 + ks] = *(const bf16x8*)(ab + mt * 49920 + ks * 1040);
  };
  auto mfma_step = [&](const uint4* Bb) {
#pragma unroll
    for (int ks = 0; ks < 4; ks++) {
      bf16x8 bra = __builtin_bit_cast(bf16x8, Bb[ks * 2]);
      bf16x8 brb = __builtin_bit_cast(bf16x8, Bb[ks * 2 + 1]);
#pragma unroll
      for (int mt = 0; mt < 2; mt++) {
        acc_ra[mt] = __builtin_amdgcn_mfma_f32_32x32x16_bf16(Af[mt * 4 + ks], bra, acc_ra[mt], 0, 0, 0);
        acc_rb[mt] = __builtin_amdgcn_mfma_f32_32x32x16_bf16(Af[mt * 4 + ks], brb, acc_rb[mt], 0, 0, 0);
      }
    }
  };

#pragma unroll
  for (int mt = 0; mt < 2; mt++)
#pragma unroll
    for (int z = 0; z < 16; z++) { acc_ra[mt][z] = 0.f; acc_rb[mt][z] = 0.f; }

  // 12 slots (kc 0..11), 3-bank rotation, prefetch 2 ahead
  int kcs = 0;
#pragma unroll 1
  for (int it = 0; it < 4; it++) {
    {
      loadB(B2);
      loadA(kcs); mfma_step(B0); kcs++;
    }
    {
      if (it < 3) loadB(B0);
      loadA(kcs); mfma_step(B1); kcs++;
    }
    {
      if (it < 3) loadB(B1);
      loadA(kcs); mfma_step(B2); kcs++;
    }
  }

  // epilogue: combine with q/k, reduce 32 d-lanes, accumulate wd halves in LDS
  {
    const int d = wd * 32 + ml;
#pragma unroll
    for (int mt = 0; mt < 2; mt++) {
      float qv[16], kv[16];
#pragma unroll
      for (int reg = 0; reg < 16; reg++) {
        int row = mt * 32 + (reg & 3) + ((reg >> 2) << 3) + (kh << 2);
        int t = 12 * (r0 + row) + c;
        int hh = t >> 14;
        int ii = (t >> 7) & 127;
        int jj = t & 127;
        qv[reg] = qkv[(size_t)((b << 7) + ii) * 2368 + (hh << 6) + d];
        kv[reg] = qkv[(size_t)((b << 7) + jj) * 2368 + 768 + (hh << 6) + d];
      }
#pragma unroll
      for (int reg = 0; reg < 16; reg++) {
        int row = mt * 32 + (reg & 3) + ((reg >> 2) << 3) + (kh << 2);
        float p = (qv[reg] + acc_ra[mt][reg]) * (kv[reg] + acc_rb[mt][reg]);
        p += __shfl_xor(p, 16);
        p += __shfl_xor(p, 8);
        p += __shfl_xor(p, 4);
        p += __shfl_xor(p, 2);
        p += __shfl_xor(p, 1);
        if (ml == 0) atomicAdd(&lds_sc[row * 6 + cc], p);
      }
    }
  }

  __syncthreads();
  if (tid < 384) {
    int row = tid / 6;
    int c2 = chalf * 6 + (tid - row * 6);
    int t = 12 * (r0 + row) + c2;
    int hh = t >> 14;
    int ii = (t >> 7) & 127;
    int jj = t & 127;
    __builtin_nontemporal_store(lds_sc[tid],
        scores + (size_t)((b * 12 + hh) * 128 + ii) * 128 + jj);
  }
}

// ---------------- attn: one (b,i) per block; softmax 13 rows + PV dots from qkv ----------------
__global__ __launch_bounds__(256)
void attn_kernel(const float* __restrict__ scores, const float* __restrict__ qkv,
                 const float* __restrict__ mask, const float* __restrict__ span,
                 float* __restrict__ ctx) {
  const int i = blockIdx.x;
  const int b = blockIdx.y;
  const int tid = threadIdx.x;
  const int l = tid & 63;
  const int wvi = tid >> 6;
  __shared__ float w[13][132];
  for (int r = wvi; r < 13; r += 4) {
    if (r < 12) {
      const float* sp = scores + (size_t)((b * 12 + r) * 128 + i) * 128;
      float s0 = sp[l] * 0.125f + mask[b * 128 + l];
      float s1 = sp[l + 64] * 0.125f + mask[b * 128 + l + 64];
      float mx = fmaxf(s0, s1);
#pragma unroll
      for (int o = 32; o; o >>= 1) mx = fmaxf(mx, __shfl_xor(mx, o));
      float e0 = __expf(s0 - mx), e1 = __expf(s1 - mx);
      float sm = e0 + e1;
#pragma unroll
      for (int o = 32; o; o >>= 1) sm += __shfl_xor(sm, o);
      float inv = 1.f / sm;
      w[r][l] = e0 * inv;
      w[r][l + 64] = e1 * inv;
    } else {
      const float* sp = span + (size_t)(b * 128 + i) * 128;
      w[12][l] = sp[l];
      w[12][l + 64] = sp[l + 64];
    }
  }
  __syncthreads();
  for (int o = tid; o < 832; o += 256) {
    int h = o >> 6, d = o & 63;
    const float* vp = qkv + (size_t)(b * 128) * 2368 + (h < 12 ? 1536 + h * 64 : 2304) + d;
    float acc = 0.f;
#pragma unroll 8
    for (int j = 0; j < 128; j++) acc += w[h][j] * vp[(size_t)j * 2368];
    ctx[(size_t)(b * 128 + i) * 832 + o] = acc;
  }
}

// ---------------- out: wave-block MFMA GEMM, full K, direct stores ----------------
// grid (24 n32, 8 m32) x 64 thr. ctx[256x832] @ Wmlp[832x768] + bmlp.
__global__ __launch_bounds__(64)
void out_kernel(const float* __restrict__ ctxb, const float* __restrict__ Wmlp,
                const float* __restrict__ bmlp, float* __restrict__ out) {
  const int n0 = blockIdx.x * 32;
  const int m0 = blockIdx.y * 32;
  const int l = threadIdx.x;
  const int rsel = l & 31, ksel = l >> 5;
  f32x16 acc;
#pragma unroll
  for (int z = 0; z < 16; z++) acc[z] = 0.f;

#pragma unroll 4
  for (int k16 = 0; k16 < 52; k16++) {
    const float* ap = ctxb + (size_t)(m0 + rsel) * 832 + k16 * 16 + ksel * 8;
    float4 a0 = *(const float4*)ap;
    float4 a1 = *(const float4*)(ap + 4);
    union { __bf16 h[8]; bf16x8 v; } pa;
    pa.h[0] = (__bf16)a0.x; pa.h[1] = (__bf16)a0.y; pa.h[2] = (__bf16)a0.z; pa.h[3] = (__bf16)a0.w;
    pa.h[4] = (__bf16)a1.x; pa.h[5] = (__bf16)a1.y; pa.h[6] = (__bf16)a1.z; pa.h[7] = (__bf16)a1.w;
    const float* bp = Wmlp + (size_t)(k16 * 16 + ksel * 8) * 768 + n0 + rsel;
    union { __bf16 h[8]; bf16x8 v; } pb;
#pragma unroll
    for (int j = 0; j < 8; j++) pb.h[j] = (__bf16)bp[(size_t)j * 768];
    acc = __builtin_amdgcn_mfma_f32_32x32x16_bf16(pa.v, pb.v, acc, 0, 0, 0);
  }
#pragma unroll
  for (int reg = 0; reg < 16; reg++) {
    int row = (reg & 3) + ((reg >> 2) << 3) + (ksel << 2);
    out[(size_t)(m0 + row) * 768 + n0 + rsel] = acc[reg] + bmlp[n0 + rsel];
  }
}

// ---------------- launch ----------------
extern "C" void kernel_launch(void* const* d_in, const int* in_sizes, int n_in,
                              void* d_out, int out_size, void* d_ws, size_t ws_size,
                              hipStream_t stream) {
  const float* hs   = (const float*)d_in[0];
  const float* mask = (const float*)d_in[1];
  const float* infp = (const float*)d_in[2];
  const float* span = (const float*)d_in[3];
  const float* Wq   = (const float*)d_in[4];
  const float* bq   = (const float*)d_in[5];
  const float* Wk   = (const float*)d_in[6];
  const float* bk   = (const float*)d_in[7];
  const float* Wv   = (const float*)d_in[8];
  const float* bv   = (const float*)d_in[9];
  const float* Wpv  = (const float*)d_in[10];
  const float* bpv  = (const float*)d_in[11];
  const float* Wip  = (const float*)d_in[12];
  const float* Wmlp = (const float*)d_in[13];
  const float* bmlp = (const float*)d_in[14];
  float* out = (float*)d_out;

  char* ws = (char*)d_ws;
  float*  qkv    = (float*)(ws + QKV_OFF);
  __bf16* arena  = (__bf16*)(ws + ARENA_OFF);
  float*  scores = (float*)(ws + SC_OFF);
  float*  ctx    = (float*)(ws + CTX_OFF);

  prep_proj_kernel<<<dim3(724), 256, 0, stream>>>(Wip, arena, hs,
      Wq, bq, Wk, bk, Wv, bv, Wpv, bpv, qkv);
  score_kernel<<<dim3(1024), 768, 101376, stream>>>(infp, arena, qkv, scores);
  attn_kernel<<<dim3(128, 2), 256, 0, stream>>>(scores, qkv, mask, span, ctx);
  out_kernel<<<dim3(24, 8), 64, 0, stream>>>(ctx, Wmlp, bmlp, out);
}

// Round 7
// 368.225 us; speedup vs baseline: 1.1102x; 1.0279x over previous
//
#include <hip/hip_runtime.h>
#include <hip/hip_bf16.h>

// B=2, S=128, H=12, DH=64, HID=768
// scores(b,h,i,j) = dot64(q+ra, k+rb)/8 + mask ; t = h*16384+i*128+j ; r=t/12, c=t%12
// ra = ip[r, 64c+d], rb = ip[r, 768+64c+d], ip = inference_path @ Wip (bf16 MFMA, never materialized)

typedef __attribute__((ext_vector_type(8))) __bf16 bf16x8;
typedef __attribute__((ext_vector_type(16))) float f32x16;
typedef __attribute__((ext_vector_type(4))) float f32x4;

// ws layout (total 7,208,960 B — proven footprint)
#define QKV_OFF   0u         // [256][2368] f32 : q|k|v|pv
#define ARENA_OFF 2424832u   // 2304 B-frags x 1KB bf16 (Wip), frag = n32*48 + k16
#define SC_OFF    4784128u   // [2][12][128][128] f32
#define CTX_OFF   6356992u   // [256][832] f32

// ---------------- fused prep+proj (independent work, one launch) ----------------
// blocks 0..575: prep — Wip [768][1536] f32 -> bf16 B-frags
// blocks 576..723: proj — 4 waves = 4 m-tiles of the wave-block MFMA GEMM
__global__ __launch_bounds__(256)
void prep_proj_kernel(const float* __restrict__ Wip, __bf16* __restrict__ arena,
                      const float* __restrict__ hs,
                      const float* __restrict__ Wq, const float* __restrict__ bq,
                      const float* __restrict__ Wk, const float* __restrict__ bk,
                      const float* __restrict__ Wv, const float* __restrict__ bv,
                      const float* __restrict__ Wpv, const float* __restrict__ bpv,
                      float* __restrict__ qkv) {
  if (blockIdx.x < 576) {
    // ---- prep: frag f = n32*48 + k16 ; lane l: col = n32*32+(l&31), k = k16*16+(l>>5)*8+j
    const int l = threadIdx.x & 63;
    const int f = blockIdx.x * 4 + (threadIdx.x >> 6);   // 0..2303
    const int n32 = f / 48, k16 = f - n32 * 48;
    const float* src = Wip + (size_t)(k16 * 16 + (l >> 5) * 8) * 1536 + n32 * 32 + (l & 31);
    union { __bf16 h[8]; uint4 u; } pk;
#pragma unroll
    for (int j = 0; j < 8; j++) pk.h[j] = (__bf16)src[(size_t)j * 1536];
    ((uint4*)arena)[(size_t)f * 64 + l] = pk.u;
    return;
  }
  // ---- proj: pblk -> (n-tile, m-quad); wave = m-tile within quad
  const int pblk = blockIdx.x - 576;                     // 0..147
  const int n0 = (pblk % 74) * 32;                       // combined col space 2368
  const int m0 = (pblk / 74) * 128 + (threadIdx.x >> 6) * 32;
  const float* W; const float* bias; int noff, ldw;
  if (n0 < 768)       { W = Wq;  bias = bq;  noff = n0;        ldw = 768; }
  else if (n0 < 1536) { W = Wk;  bias = bk;  noff = n0 - 768;  ldw = 768; }
  else if (n0 < 2304) { W = Wv;  bias = bv;  noff = n0 - 1536; ldw = 768; }
  else                { W = Wpv; bias = bpv; noff = n0 - 2304; ldw = 64;  }
  const int l = threadIdx.x & 63;
  const int rsel = l & 31, ksel = l >> 5;
  f32x16 acc;
#pragma unroll
  for (int z = 0; z < 16; z++) acc[z] = 0.f;

#pragma unroll 4
  for (int k16 = 0; k16 < 48; k16++) {
    const float* ap = hs + (size_t)(m0 + rsel) * 768 + k16 * 16 + ksel * 8;
    float4 a0 = *(const float4*)ap;
    float4 a1 = *(const float4*)(ap + 4);
    union { __bf16 h[8]; bf16x8 v; } pa;
    pa.h[0] = (__bf16)a0.x; pa.h[1] = (__bf16)a0.y; pa.h[2] = (__bf16)a0.z; pa.h[3] = (__bf16)a0.w;
    pa.h[4] = (__bf16)a1.x; pa.h[5] = (__bf16)a1.y; pa.h[6] = (__bf16)a1.z; pa.h[7] = (__bf16)a1.w;
    const float* bp = W + (size_t)(k16 * 16 + ksel * 8) * ldw + noff + rsel;
    union { __bf16 h[8]; bf16x8 v; } pb;
#pragma unroll
    for (int j = 0; j < 8; j++) pb.h[j] = (__bf16)bp[(size_t)j * ldw];
    acc = __builtin_amdgcn_mfma_f32_32x32x16_bf16(pa.v, pb.v, acc, 0, 0, 0);
  }
#pragma unroll
  for (int reg = 0; reg < 16; reg++) {
    int row = (reg & 3) + ((reg >> 2) << 3) + (ksel << 2);
    qkv[(size_t)(m0 + row) * 2368 + n0 + rsel] = acc[reg] + bias[noff + rsel];
  }
}

// ---------------- score: fused ip-GEMM + score reduction (R2-proven, 141 us) ----------------
// v3: depth-2 B prefetch (3 register banks, unroll-3 loop, static indices) +
// nontemporal infp staging. Compiler-scheduled loads, no spill.
extern __shared__ char smem_raw[];

__global__ __launch_bounds__(512, 2)
void score_kernel(const float* __restrict__ infp,
                  const __bf16* __restrict__ arena,
                  const float* __restrict__ qkv,
                  float* __restrict__ scores) {
  char* Abase = smem_raw;                        // 96 frags * 1040 = 99840 B
  float* lds_sc = (float*)(smem_raw + 99840);    // 64*12 floats
  const int tid = threadIdx.x;
  const int lane = tid & 63;
  const int ml = lane & 31;
  const int kh = lane >> 5;
  const int wv = tid >> 6;
  const int wc = wv & 3;
  const int wd = wv >> 2;
  const int blk = blockIdx.x;
  const int b = blk >> 8;
  const int r0 = (blk & 255) << 6;

  for (int z = tid; z < 768; z += 512) lds_sc[z] = 0.f;

  const uint4* BA = (const uint4*)arena;
  const uint4* bptr  = BA + (size_t)((2 * wc + wd) * 48) * 64 + lane;
  const uint4* bptr2 = bptr + 73728;
  int kpn = 0;                                   // kc the pointer targets
  uint4 B0[8], B1[8], B2[8];
  bf16x8 Af[8];
  f32x16 acc_ra[2], acc_rb[2];

  auto loadB = [&](uint4* dst) {
#pragma unroll
    for (int ks = 0; ks < 4; ks++) {
      dst[ks * 2]     = bptr[ks * 64];           // ra (cols < 768)
      dst[ks * 2 + 1] = bptr2[ks * 64];          // rb (+1152 frags)
    }
    if (kpn == 11) { bptr += 21760; bptr2 += 21760; kpn = 0; }
    else           { bptr += 256;   bptr2 += 256;   kpn++;  }
  };

  // prefetch B for slots 0 and 1: overlaps the HBM A-staging below
  loadB(B0);
  loadB(B1);

  // stage A: 64 rows x 768 f32 -> bf16 frag-ordered LDS (HBM read-once, nt)
  {
    const f32x4* A4 = (const f32x4*)(infp + (size_t)(b * 16384 + r0) * 768);
#pragma unroll
    for (int p = 0; p < 12; p++) {
      int idx = p * 512 + tid;
      int m = (int)(((unsigned)idx * 10923u) >> 20);   // idx/96
      int g = idx - m * 96;
      f32x4 v0 = __builtin_nontemporal_load(A4 + m * 192 + g * 2);
      f32x4 v1 = __builtin_nontemporal_load(A4 + m * 192 + g * 2 + 1);
      union { __bf16 h[8]; uint4 u; } pk;
      pk.h[0] = (__bf16)v0[0]; pk.h[1] = (__bf16)v0[1];
      pk.h[2] = (__bf16)v0[2]; pk.h[3] = (__bf16)v0[3];
      pk.h[4] = (__bf16)v1[0]; pk.h[5] = (__bf16)v1[1];
      pk.h[6] = (__bf16)v1[2]; pk.h[7] = (__bf16)v1[3];
      int F = (m >> 5) * 48 + (g >> 1);
      int slot = (m & 31) + ((g & 1) << 5);
      *(uint4*)(Abase + ((F * 65 + slot) << 4)) = pk.u;
    }
  }
  __syncthreads();

  const size_t lane_off = (size_t)(lane << 4);
  auto loadA = [&](int kcc) {
    const char* ab = Abase + lane_off + kcc * 4160;
#pragma unroll
    for (int mt = 0; mt < 2; mt++)
#pragma unroll
      for (int ks = 0; ks < 4; ks++)
        Af[mt * 4 + ks] = *(const bf16x8*)(ab + mt * 49920 + ks * 1040);
  };
  auto mfma_step = [&](const uint4* Bb) {
#pragma unroll
    for (int ks = 0; ks < 4; ks++) {
      bf16x8 bra = __builtin_bit_cast(bf16x8, Bb[ks * 2]);
      bf16x8 brb = __builtin_bit_cast(bf16x8, Bb[ks * 2 + 1]);
#pragma unroll
      for (int mt = 0; mt < 2; mt++) {
        acc_ra[mt] = __builtin_amdgcn_mfma_f32_32x32x16_bf16(Af[mt * 4 + ks], bra, acc_ra[mt], 0, 0, 0);
        acc_rb[mt] = __builtin_amdgcn_mfma_f32_32x32x16_bf16(Af[mt * 4 + ks], brb, acc_rb[mt], 0, 0, 0);
      }
    }
  };
  auto epilogue = [&](int c) {
    int d = wd * 32 + ml;
#pragma unroll
    for (int mt = 0; mt < 2; mt++) {
      float qv[16], kv[16];
#pragma unroll
      for (int reg = 0; reg < 16; reg++) {
        int row = mt * 32 + (reg & 3) + ((reg >> 2) << 3) + (kh << 2);
        int t = 12 * (r0 + row) + c;
        int hh = t >> 14;
        int ii = (t >> 7) & 127;
        int jj = t & 127;
        qv[reg] = qkv[(size_t)((b << 7) + ii) * 2368 + (hh << 6) + d];
        kv[reg] = qkv[(size_t)((b << 7) + jj) * 2368 + 768 + (hh << 6) + d];
      }
#pragma unroll
      for (int reg = 0; reg < 16; reg++) {
        int row = mt * 32 + (reg & 3) + ((reg >> 2) << 3) + (kh << 2);
        float p = (qv[reg] + acc_ra[mt][reg]) * (kv[reg] + acc_rb[mt][reg]);
        p += __shfl_xor(p, 16);
        p += __shfl_xor(p, 8);
        p += __shfl_xor(p, 4);
        p += __shfl_xor(p, 2);
        p += __shfl_xor(p, 1);
        if (ml == 0) atomicAdd(&lds_sc[row * 12 + c], p);
      }
    }
#pragma unroll
    for (int mt = 0; mt < 2; mt++)
#pragma unroll
      for (int z = 0; z < 16; z++) { acc_ra[mt][z] = 0.f; acc_rb[mt][z] = 0.f; }
  };

#pragma unroll
  for (int mt = 0; mt < 2; mt++)
#pragma unroll
    for (int z = 0; z < 16; z++) { acc_ra[mt][z] = 0.f; acc_rb[mt][z] = 0.f; }

  // 36 slots = 12 iters x 3, banks rotate statically: consume B0,B1,B2 ;
  // slot t prefetches slot t+2's frags into the bank freed at t-1.
  int kcc = 0, cc = wc;
#pragma unroll 1
  for (int it = 0; it < 12; it++) {
    {  // slot 3it+0 : consume B0, prefetch slot 3it+2 -> B2
      loadB(B2);
      loadA(kcc);
      mfma_step(B0);
      if (kcc == 11) { epilogue(cc); kcc = 0; cc += 4; } else kcc++;
    }
    {  // slot 3it+1 : consume B1, prefetch slot 3it+3 -> B0
      if (it < 11) loadB(B0);
      loadA(kcc);
      mfma_step(B1);
      if (kcc == 11) { epilogue(cc); kcc = 0; cc += 4; } else kcc++;
    }
    {  // slot 3it+2 : consume B2, prefetch slot 3it+4 -> B1
      if (it < 11) loadB(B1);
      loadA(kcc);
      mfma_step(B2);
      if (kcc == 11) { epilogue(cc); kcc = 0; cc += 4; } else kcc++;
    }
  }

  __syncthreads();
  for (int z = tid; z < 768; z += 512) {
    int row = z / 12;
    int ccc = z - row * 12;
    int t = 12 * (r0 + row) + ccc;
    int hh = t >> 14;
    int ii = (t >> 7) & 127;
    int jj = t & 127;
    scores[(size_t)((b * 12 + hh) * 128 + ii) * 128 + jj] = lds_sc[z];
  }
}

// ---------------- attn v2: 8 blocks x 8 waves, MFMA PV ----------------
// block (b, q0=32 rows). 4 rounds: rounds 0..2 = head-quads (softmax 4h into
// LDS w4, then 8 waves each run one (h, n-tile) 32x32x16 MFMA K-loop over j);
// round 3 = span (identity weights, 2 wave-jobs). ctx written directly.
__global__ __launch_bounds__(512)
void attn_kernel(const float* __restrict__ scores, const float* __restrict__ qkv,
                 const float* __restrict__ mask, const float* __restrict__ span,
                 float* __restrict__ ctx) {
  __shared__ float w4[4][32][132];               // 67.6 KB
  const int blk = blockIdx.x;                    // 0..7
  const int b = blk >> 2;
  const int q0 = (blk & 3) << 5;
  const int tid = threadIdx.x;
  const int lane = tid & 63;
  const int wv = tid >> 6;                       // 0..7
  const int rsel = lane & 31, ksel = lane >> 5;

#pragma unroll 1
  for (int rnd = 0; rnd < 4; rnd++) {
    // --- fill w4 (softmax or span copy) ---
    if (rnd < 3) {
#pragma unroll 1
      for (int s = 0; s < 16; s++) {
        int job = s * 8 + wv;                    // 0..127
        int hq = job >> 5;
        int i  = job & 31;
        int h  = rnd * 4 + hq;
        const float* sp = scores + (size_t)((b * 12 + h) * 128 + (q0 + i)) * 128;
        float s0 = sp[lane] * 0.125f + mask[b * 128 + lane];
        float s1 = sp[lane + 64] * 0.125f + mask[b * 128 + lane + 64];
        float mx = fmaxf(s0, s1);
#pragma unroll
        for (int o = 32; o; o >>= 1) mx = fmaxf(mx, __shfl_xor(mx, o));
        float e0 = __expf(s0 - mx), e1 = __expf(s1 - mx);
        float sm = e0 + e1;
#pragma unroll
        for (int o = 32; o; o >>= 1) sm += __shfl_xor(sm, o);
        float inv = 1.f / sm;
        w4[hq][i][lane] = e0 * inv;
        w4[hq][i][lane + 64] = e1 * inv;
      }
    } else {
#pragma unroll 1
      for (int s = 0; s < 4; s++) {
        int i = s * 8 + wv;
        const float* sp = span + (size_t)(b * 16384) + (size_t)(q0 + i) * 128;
        w4[0][i][lane] = sp[lane];
        w4[0][i][lane + 64] = sp[lane + 64];
      }
    }
    __syncthreads();
    // --- PV: wave job = (hq, nt) ---
    const int njobs = (rnd < 3) ? 8 : 2;
    if (wv < njobs) {
      const int hq = wv >> 1, nt = wv & 1;
      int vcol, ocol;
      if (rnd < 3) { int h = rnd * 4 + hq; vcol = 1536 + h * 64 + nt * 32; ocol = h * 64 + nt * 32; }
      else         { vcol = 2304 + nt * 32; ocol = 768 + nt * 32; }
      f32x16 acc;
#pragma unroll
      for (int z = 0; z < 16; z++) acc[z] = 0.f;
#pragma unroll
      for (int k16 = 0; k16 < 8; k16++) {
        const float* ap = &w4[hq][rsel][k16 * 16 + ksel * 8];
        float4 a0 = *(const float4*)ap;
        float4 a1 = *(const float4*)(ap + 4);
        union { __bf16 h[8]; bf16x8 v; } pa;
        pa.h[0] = (__bf16)a0.x; pa.h[1] = (__bf16)a0.y; pa.h[2] = (__bf16)a0.z; pa.h[3] = (__bf16)a0.w;
        pa.h[4] = (__bf16)a1.x; pa.h[5] = (__bf16)a1.y; pa.h[6] = (__bf16)a1.z; pa.h[7] = (__bf16)a1.w;
        const float* bp = qkv + (size_t)(b * 128 + k16 * 16 + ksel * 8) * 2368 + vcol + rsel;
        union { __bf16 h[8]; bf16x8 v; } pb;
#pragma unroll
        for (int j = 0; j < 8; j++) pb.h[j] = (__bf16)bp[(size_t)j * 2368];
        acc = __builtin_amdgcn_mfma_f32_32x32x16_bf16(pa.v, pb.v, acc, 0, 0, 0);
      }
#pragma unroll
      for (int reg = 0; reg < 16; reg++) {
        int row = (reg & 3) + ((reg >> 2) << 3) + (ksel << 2);
        ctx[(size_t)(b * 128 + q0 + row) * 832 + ocol + rsel] = acc[reg];
      }
    }
    __syncthreads();
  }
}

// ---------------- out v2: (24 n-tiles, 2 m-supers) x 256 thr (4 waves = 4 m-tiles) ----------------
// 4 waves share the Wmlp fragment stream (L1 hits); Wmlp HBM traffic 20->4.7 MB.
__global__ __launch_bounds__(256)
void out_kernel(const float* __restrict__ ctxb, const float* __restrict__ Wmlp,
                const float* __restrict__ bmlp, float* __restrict__ out) {
  const int n0 = blockIdx.x * 32;
  const int m0 = blockIdx.y * 128 + (threadIdx.x >> 6) * 32;
  const int l = threadIdx.x & 63;
  const int rsel = l & 31, ksel = l >> 5;
  f32x16 acc;
#pragma unroll
  for (int z = 0; z < 16; z++) acc[z] = 0.f;

#pragma unroll 4
  for (int k16 = 0; k16 < 52; k16++) {
    const float* ap = ctxb + (size_t)(m0 + rsel) * 832 + k16 * 16 + ksel * 8;
    float4 a0 = *(const float4*)ap;
    float4 a1 = *(const float4*)(ap + 4);
    union { __bf16 h[8]; bf16x8 v; } pa;
    pa.h[0] = (__bf16)a0.x; pa.h[1] = (__bf16)a0.y; pa.h[2] = (__bf16)a0.z; pa.h[3] = (__bf16)a0.w;
    pa.h[4] = (__bf16)a1.x; pa.h[5] = (__bf16)a1.y; pa.h[6] = (__bf16)a1.z; pa.h[7] = (__bf16)a1.w;
    const float* bp = Wmlp + (size_t)(k16 * 16 + ksel * 8) * 768 + n0 + rsel;
    union { __bf16 h[8]; bf16x8 v; } pb;
#pragma unroll
    for (int j = 0; j < 8; j++) pb.h[j] = (__bf16)bp[(size_t)j * 768];
    acc = __builtin_amdgcn_mfma_f32_32x32x16_bf16(pa.v, pb.v, acc, 0, 0, 0);
  }
#pragma unroll
  for (int reg = 0; reg < 16; reg++) {
    int row = (reg & 3) + ((reg >> 2) << 3) + (ksel << 2);
    out[(size_t)(m0 + row) * 768 + n0 + rsel] = acc[reg] + bmlp[n0 + rsel];
  }
}

// ---------------- launch ----------------
extern "C" void kernel_launch(void* const* d_in, const int* in_sizes, int n_in,
                              void* d_out, int out_size, void* d_ws, size_t ws_size,
                              hipStream_t stream) {
  const float* hs   = (const float*)d_in[0];
  const float* mask = (const float*)d_in[1];
  const float* infp = (const float*)d_in[2];
  const float* span = (const float*)d_in[3];
  const float* Wq   = (const float*)d_in[4];
  const float* bq   = (const float*)d_in[5];
  const float* Wk   = (const float*)d_in[6];
  const float* bk   = (const float*)d_in[7];
  const float* Wv   = (const float*)d_in[8];
  const float* bv   = (const float*)d_in[9];
  const float* Wpv  = (const float*)d_in[10];
  const float* bpv  = (const float*)d_in[11];
  const float* Wip  = (const float*)d_in[12];
  const float* Wmlp = (const float*)d_in[13];
  const float* bmlp = (const float*)d_in[14];
  float* out = (float*)d_out;

  char* ws = (char*)d_ws;
  float*  qkv    = (float*)(ws + QKV_OFF);
  __bf16* arena  = (__bf16*)(ws + ARENA_OFF);
  float*  scores = (float*)(ws + SC_OFF);
  float*  ctx    = (float*)(ws + CTX_OFF);

  prep_proj_kernel<<<dim3(724), 256, 0, stream>>>(Wip, arena, hs,
      Wq, bq, Wk, bk, Wv, bv, Wpv, bpv, qkv);
  score_kernel<<<dim3(512), 512, 102912, stream>>>(infp, arena, qkv, scores);
  attn_kernel<<<dim3(8), 512, 0, stream>>>(scores, qkv, mask, span, ctx);
  out_kernel<<<dim3(24, 2), 256, 0, stream>>>(ctx, Wmlp, bmlp, out);
}

// Round 8
// 349.694 us; speedup vs baseline: 1.1690x; 1.0530x over previous
//
#include <hip/hip_runtime.h>
#include <hip/hip_bf16.h>

// B=2, S=128, H=12, DH=64, HID=768
// scores(b,h,i,j) = dot64(q+ra, k+rb)/8 + mask ; t = h*16384+i*128+j ; r=t/12, c=t%12
// ra = ip[r, 64c+d], rb = ip[r, 768+64c+d], ip = inference_path @ Wip (bf16 MFMA, never materialized)

typedef __attribute__((ext_vector_type(8))) __bf16 bf16x8;
typedef __attribute__((ext_vector_type(16))) float f32x16;
typedef __attribute__((ext_vector_type(4))) float f32x4;

// ws layout (total 7,208,960 B — proven footprint)
#define QKV_OFF   0u         // [256][2368] f32 : q|k|v|pv
#define ARENA_OFF 2424832u   // 2304 B-frags x 1KB bf16 (Wip), frag = n32*48 + k16
#define SC_OFF    4784128u   // [2][12][128][128] f32
#define CTX_OFF   6356992u   // [256][832] f32

// ---------------- fused prep+proj (independent work, one launch) ----------------
// blocks 0..575: prep — Wip [768][1536] f32 -> bf16 B-frags
// blocks 576..723: proj — 4 waves = 4 m-tiles of the wave-block MFMA GEMM
__global__ __launch_bounds__(256)
void prep_proj_kernel(const float* __restrict__ Wip, __bf16* __restrict__ arena,
                      const float* __restrict__ hs,
                      const float* __restrict__ Wq, const float* __restrict__ bq,
                      const float* __restrict__ Wk, const float* __restrict__ bk,
                      const float* __restrict__ Wv, const float* __restrict__ bv,
                      const float* __restrict__ Wpv, const float* __restrict__ bpv,
                      float* __restrict__ qkv) {
  if (blockIdx.x < 576) {
    // ---- prep: frag f = n32*48 + k16 ; lane l: col = n32*32+(l&31), k = k16*16+(l>>5)*8+j
    const int l = threadIdx.x & 63;
    const int f = blockIdx.x * 4 + (threadIdx.x >> 6);   // 0..2303
    const int n32 = f / 48, k16 = f - n32 * 48;
    const float* src = Wip + (size_t)(k16 * 16 + (l >> 5) * 8) * 1536 + n32 * 32 + (l & 31);
    union { __bf16 h[8]; uint4 u; } pk;
#pragma unroll
    for (int j = 0; j < 8; j++) pk.h[j] = (__bf16)src[(size_t)j * 1536];
    ((uint4*)arena)[(size_t)f * 64 + l] = pk.u;
    return;
  }
  // ---- proj: pblk -> (n-tile, m-quad); wave = m-tile within quad
  const int pblk = blockIdx.x - 576;                     // 0..147
  const int n0 = (pblk % 74) * 32;                       // combined col space 2368
  const int m0 = (pblk / 74) * 128 + (threadIdx.x >> 6) * 32;
  const float* W; const float* bias; int noff, ldw;
  if (n0 < 768)       { W = Wq;  bias = bq;  noff = n0;        ldw = 768; }
  else if (n0 < 1536) { W = Wk;  bias = bk;  noff = n0 - 768;  ldw = 768; }
  else if (n0 < 2304) { W = Wv;  bias = bv;  noff = n0 - 1536; ldw = 768; }
  else                { W = Wpv; bias = bpv; noff = n0 - 2304; ldw = 64;  }
  const int l = threadIdx.x & 63;
  const int rsel = l & 31, ksel = l >> 5;
  f32x16 acc;
#pragma unroll
  for (int z = 0; z < 16; z++) acc[z] = 0.f;

#pragma unroll 4
  for (int k16 = 0; k16 < 48; k16++) {
    const float* ap = hs + (size_t)(m0 + rsel) * 768 + k16 * 16 + ksel * 8;
    float4 a0 = *(const float4*)ap;
    float4 a1 = *(const float4*)(ap + 4);
    union { __bf16 h[8]; bf16x8 v; } pa;
    pa.h[0] = (__bf16)a0.x; pa.h[1] = (__bf16)a0.y; pa.h[2] = (__bf16)a0.z; pa.h[3] = (__bf16)a0.w;
    pa.h[4] = (__bf16)a1.x; pa.h[5] = (__bf16)a1.y; pa.h[6] = (__bf16)a1.z; pa.h[7] = (__bf16)a1.w;
    const float* bp = W + (size_t)(k16 * 16 + ksel * 8) * ldw + noff + rsel;
    union { __bf16 h[8]; bf16x8 v; } pb;
#pragma unroll
    for (int j = 0; j < 8; j++) pb.h[j] = (__bf16)bp[(size_t)j * ldw];
    acc = __builtin_amdgcn_mfma_f32_32x32x16_bf16(pa.v, pb.v, acc, 0, 0, 0);
  }
#pragma unroll
  for (int reg = 0; reg < 16; reg++) {
    int row = (reg & 3) + ((reg >> 2) << 3) + (ksel << 2);
    qkv[(size_t)(m0 + row) * 2368 + n0 + rsel] = acc[reg] + bias[noff + rsel];
  }
}

// ---------------- score: fused ip-GEMM + score reduction (R2-proven) ----------------
// v3: depth-2 B prefetch (3 register banks, unroll-3 loop, static indices) +
// nontemporal infp staging. Compiler-scheduled loads, no spill. FROZEN.
extern __shared__ char smem_raw[];

__global__ __launch_bounds__(512, 2)
void score_kernel(const float* __restrict__ infp,
                  const __bf16* __restrict__ arena,
                  const float* __restrict__ qkv,
                  float* __restrict__ scores) {
  char* Abase = smem_raw;                        // 96 frags * 1040 = 99840 B
  float* lds_sc = (float*)(smem_raw + 99840);    // 64*12 floats
  const int tid = threadIdx.x;
  const int lane = tid & 63;
  const int ml = lane & 31;
  const int kh = lane >> 5;
  const int wv = tid >> 6;
  const int wc = wv & 3;
  const int wd = wv >> 2;
  const int blk = blockIdx.x;
  const int b = blk >> 8;
  const int r0 = (blk & 255) << 6;

  for (int z = tid; z < 768; z += 512) lds_sc[z] = 0.f;

  const uint4* BA = (const uint4*)arena;
  const uint4* bptr  = BA + (size_t)((2 * wc + wd) * 48) * 64 + lane;
  const uint4* bptr2 = bptr + 73728;
  int kpn = 0;                                   // kc the pointer targets
  uint4 B0[8], B1[8], B2[8];
  bf16x8 Af[8];
  f32x16 acc_ra[2], acc_rb[2];

  auto loadB = [&](uint4* dst) {
#pragma unroll
    for (int ks = 0; ks < 4; ks++) {
      dst[ks * 2]     = bptr[ks * 64];           // ra (cols < 768)
      dst[ks * 2 + 1] = bptr2[ks * 64];          // rb (+1152 frags)
    }
    if (kpn == 11) { bptr += 21760; bptr2 += 21760; kpn = 0; }
    else           { bptr += 256;   bptr2 += 256;   kpn++;  }
  };

  // prefetch B for slots 0 and 1: overlaps the HBM A-staging below
  loadB(B0);
  loadB(B1);

  // stage A: 64 rows x 768 f32 -> bf16 frag-ordered LDS (HBM read-once, nt)
  {
    const f32x4* A4 = (const f32x4*)(infp + (size_t)(b * 16384 + r0) * 768);
#pragma unroll
    for (int p = 0; p < 12; p++) {
      int idx = p * 512 + tid;
      int m = (int)(((unsigned)idx * 10923u) >> 20);   // idx/96
      int g = idx - m * 96;
      f32x4 v0 = __builtin_nontemporal_load(A4 + m * 192 + g * 2);
      f32x4 v1 = __builtin_nontemporal_load(A4 + m * 192 + g * 2 + 1);
      union { __bf16 h[8]; uint4 u; } pk;
      pk.h[0] = (__bf16)v0[0]; pk.h[1] = (__bf16)v0[1];
      pk.h[2] = (__bf16)v0[2]; pk.h[3] = (__bf16)v0[3];
      pk.h[4] = (__bf16)v1[0]; pk.h[5] = (__bf16)v1[1];
      pk.h[6] = (__bf16)v1[2]; pk.h[7] = (__bf16)v1[3];
      int F = (m >> 5) * 48 + (g >> 1);
      int slot = (m & 31) + ((g & 1) << 5);
      *(uint4*)(Abase + ((F * 65 + slot) << 4)) = pk.u;
    }
  }
  __syncthreads();

  const size_t lane_off = (size_t)(lane << 4);
  auto loadA = [&](int kcc) {
    const char* ab = Abase + lane_off + kcc * 4160;
#pragma unroll
    for (int mt = 0; mt < 2; mt++)
#pragma unroll
      for (int ks = 0; ks < 4; ks++)
        Af[mt * 4 + ks] = *(const bf16x8*)(ab + mt * 49920 + ks * 1040);
  };
  auto mfma_step = [&](const uint4* Bb) {
#pragma unroll
    for (int ks = 0; ks < 4; ks++) {
      bf16x8 bra = __builtin_bit_cast(bf16x8, Bb[ks * 2]);
      bf16x8 brb = __builtin_bit_cast(bf16x8, Bb[ks * 2 + 1]);
#pragma unroll
      for (int mt = 0; mt < 2; mt++) {
        acc_ra[mt] = __builtin_amdgcn_mfma_f32_32x32x16_bf16(Af[mt * 4 + ks], bra, acc_ra[mt], 0, 0, 0);
        acc_rb[mt] = __builtin_amdgcn_mfma_f32_32x32x16_bf16(Af[mt * 4 + ks], brb, acc_rb[mt], 0, 0, 0);
      }
    }
  };
  auto epilogue = [&](int c) {
    int d = wd * 32 + ml;
#pragma unroll
    for (int mt = 0; mt < 2; mt++) {
      float qv[16], kv[16];
#pragma unroll
      for (int reg = 0; reg < 16; reg++) {
        int row = mt * 32 + (reg & 3) + ((reg >> 2) << 3) + (kh << 2);
        int t = 12 * (r0 + row) + c;
        int hh = t >> 14;
        int ii = (t >> 7) & 127;
        int jj = t & 127;
        qv[reg] = qkv[(size_t)((b << 7) + ii) * 2368 + (hh << 6) + d];
        kv[reg] = qkv[(size_t)((b << 7) + jj) * 2368 + 768 + (hh << 6) + d];
      }
#pragma unroll
      for (int reg = 0; reg < 16; reg++) {
        int row = mt * 32 + (reg & 3) + ((reg >> 2) << 3) + (kh << 2);
        float p = (qv[reg] + acc_ra[mt][reg]) * (kv[reg] + acc_rb[mt][reg]);
        p += __shfl_xor(p, 16);
        p += __shfl_xor(p, 8);
        p += __shfl_xor(p, 4);
        p += __shfl_xor(p, 2);
        p += __shfl_xor(p, 1);
        if (ml == 0) atomicAdd(&lds_sc[row * 12 + c], p);
      }
    }
#pragma unroll
    for (int mt = 0; mt < 2; mt++)
#pragma unroll
      for (int z = 0; z < 16; z++) { acc_ra[mt][z] = 0.f; acc_rb[mt][z] = 0.f; }
  };

#pragma unroll
  for (int mt = 0; mt < 2; mt++)
#pragma unroll
    for (int z = 0; z < 16; z++) { acc_ra[mt][z] = 0.f; acc_rb[mt][z] = 0.f; }

  // 36 slots = 12 iters x 3, banks rotate statically: consume B0,B1,B2 ;
  // slot t prefetches slot t+2's frags into the bank freed at t-1.
  int kcc = 0, cc = wc;
#pragma unroll 1
  for (int it = 0; it < 12; it++) {
    {  // slot 3it+0 : consume B0, prefetch slot 3it+2 -> B2
      loadB(B2);
      loadA(kcc);
      mfma_step(B0);
      if (kcc == 11) { epilogue(cc); kcc = 0; cc += 4; } else kcc++;
    }
    {  // slot 3it+1 : consume B1, prefetch slot 3it+3 -> B0
      if (it < 11) loadB(B0);
      loadA(kcc);
      mfma_step(B1);
      if (kcc == 11) { epilogue(cc); kcc = 0; cc += 4; } else kcc++;
    }
    {  // slot 3it+2 : consume B2, prefetch slot 3it+4 -> B1
      if (it < 11) loadB(B1);
      loadA(kcc);
      mfma_step(B2);
      if (kcc == 11) { epilogue(cc); kcc = 0; cc += 4; } else kcc++;
    }
  }

  __syncthreads();
  for (int z = tid; z < 768; z += 512) {
    int row = z / 12;
    int ccc = z - row * 12;
    int t = 12 * (r0 + row) + ccc;
    int hh = t >> 14;
    int ii = (t >> 7) & 127;
    int jj = t & 127;
    scores[(size_t)((b * 12 + hh) * 128 + ii) * 128 + jj] = lds_sc[z];
  }
}

// ---------------- attn: one (b,i) per block; softmax 13 rows + PV dots (R0-proven) ----------------
__global__ __launch_bounds__(256)
void attn_kernel(const float* __restrict__ scores, const float* __restrict__ qkv,
                 const float* __restrict__ mask, const float* __restrict__ span,
                 float* __restrict__ ctx) {
  const int i = blockIdx.x;
  const int b = blockIdx.y;
  const int tid = threadIdx.x;
  const int l = tid & 63;
  const int wvi = tid >> 6;
  __shared__ float w[13][132];
  for (int r = wvi; r < 13; r += 4) {
    if (r < 12) {
      const float* sp = scores + (size_t)((b * 12 + r) * 128 + i) * 128;
      float s0 = sp[l] * 0.125f + mask[b * 128 + l];
      float s1 = sp[l + 64] * 0.125f + mask[b * 128 + l + 64];
      float mx = fmaxf(s0, s1);
#pragma unroll
      for (int o = 32; o; o >>= 1) mx = fmaxf(mx, __shfl_xor(mx, o));
      float e0 = __expf(s0 - mx), e1 = __expf(s1 - mx);
      float sm = e0 + e1;
#pragma unroll
      for (int o = 32; o; o >>= 1) sm += __shfl_xor(sm, o);
      float inv = 1.f / sm;
      w[r][l] = e0 * inv;
      w[r][l + 64] = e1 * inv;
    } else {
      const float* sp = span + (size_t)(b * 128 + i) * 128;
      w[12][l] = sp[l];
      w[12][l + 64] = sp[l + 64];
    }
  }
  __syncthreads();
  for (int o = tid; o < 832; o += 256) {
    int h = o >> 6, d = o & 63;
    const float* vp = qkv + (size_t)(b * 128) * 2368 + (h < 12 ? 1536 + h * 64 : 2304) + d;
    float acc = 0.f;
#pragma unroll 8
    for (int j = 0; j < 128; j++) acc += w[h][j] * vp[(size_t)j * 2368];
    ctx[(size_t)(b * 128 + i) * 832 + o] = acc;
  }
}

// ---------------- out v2: (24 n-tiles, 2 m-supers) x 256 thr (4 waves = 4 m-tiles) ----------------
// 4 waves share the Wmlp fragment stream (L1 hits).
__global__ __launch_bounds__(256)
void out_kernel(const float* __restrict__ ctxb, const float* __restrict__ Wmlp,
                const float* __restrict__ bmlp, float* __restrict__ out) {
  const int n0 = blockIdx.x * 32;
  const int m0 = blockIdx.y * 128 + (threadIdx.x >> 6) * 32;
  const int l = threadIdx.x & 63;
  const int rsel = l & 31, ksel = l >> 5;
  f32x16 acc;
#pragma unroll
  for (int z = 0; z < 16; z++) acc[z] = 0.f;

#pragma unroll 4
  for (int k16 = 0; k16 < 52; k16++) {
    const float* ap = ctxb + (size_t)(m0 + rsel) * 832 + k16 * 16 + ksel * 8;
    float4 a0 = *(const float4*)ap;
    float4 a1 = *(const float4*)(ap + 4);
    union { __bf16 h[8]; bf16x8 v; } pa;
    pa.h[0] = (__bf16)a0.x; pa.h[1] = (__bf16)a0.y; pa.h[2] = (__bf16)a0.z; pa.h[3] = (__bf16)a0.w;
    pa.h[4] = (__bf16)a1.x; pa.h[5] = (__bf16)a1.y; pa.h[6] = (__bf16)a1.z; pa.h[7] = (__bf16)a1.w;
    const float* bp = Wmlp + (size_t)(k16 * 16 + ksel * 8) * 768 + n0 + rsel;
    union { __bf16 h[8]; bf16x8 v; } pb;
#pragma unroll
    for (int j = 0; j < 8; j++) pb.h[j] = (__bf16)bp[(size_t)j * 768];
    acc = __builtin_amdgcn_mfma_f32_32x32x16_bf16(pa.v, pb.v, acc, 0, 0, 0);
  }
#pragma unroll
  for (int reg = 0; reg < 16; reg++) {
    int row = (reg & 3) + ((reg >> 2) << 3) + (ksel << 2);
    out[(size_t)(m0 + row) * 768 + n0 + rsel] = acc[reg] + bmlp[n0 + rsel];
  }
}

// ---------------- launch ----------------
extern "C" void kernel_launch(void* const* d_in, const int* in_sizes, int n_in,
                              void* d_out, int out_size, void* d_ws, size_t ws_size,
                              hipStream_t stream) {
  const float* hs   = (const float*)d_in[0];
  const float* mask = (const float*)d_in[1];
  const float* infp = (const float*)d_in[2];
  const float* span = (const float*)d_in[3];
  const float* Wq   = (const float*)d_in[4];
  const float* bq   = (const float*)d_in[5];
  const float* Wk   = (const float*)d_in[6];
  const float* bk   = (const float*)d_in[7];
  const float* Wv   = (const float*)d_in[8];
  const float* bv   = (const float*)d_in[9];
  const float* Wpv  = (const float*)d_in[10];
  const float* bpv  = (const float*)d_in[11];
  const float* Wip  = (const float*)d_in[12];
  const float* Wmlp = (const float*)d_in[13];
  const float* bmlp = (const float*)d_in[14];
  float* out = (float*)d_out;

  char* ws = (char*)d_ws;
  float*  qkv    = (float*)(ws + QKV_OFF);
  __bf16* arena  = (__bf16*)(ws + ARENA_OFF);
  float*  scores = (float*)(ws + SC_OFF);
  float*  ctx    = (float*)(ws + CTX_OFF);

  prep_proj_kernel<<<dim3(724), 256, 0, stream>>>(Wip, arena, hs,
      Wq, bq, Wk, bk, Wv, bv, Wpv, bpv, qkv);
  score_kernel<<<dim3(512), 512, 102912, stream>>>(infp, arena, qkv, scores);
  attn_kernel<<<dim3(128, 2), 256, 0, stream>>>(scores, qkv, mask, span, ctx);
  out_kernel<<<dim3(24, 2), 256, 0, stream>>>(ctx, Wmlp, bmlp, out);
}

// Round 9
// 321.496 us; speedup vs baseline: 1.2716x; 1.0877x over previous
//
#include <hip/hip_runtime.h>
#include <hip/hip_bf16.h>

// B=2, S=128, H=12, DH=64, HID=768
// scores(b,h,i,j) = dot64(q+ra, k+rb)/8 + mask ; t = h*16384+i*128+j ; r=t/12, c=t%12
// ra = ip[r, 64c+d], rb = ip[r, 768+64c+d], ip = inference_path @ Wip (bf16 MFMA, never materialized)
// score block (b,r0) covers t in [12*r0, 12*r0+768) = 6 COMPLETE (h,i) rows -> softmax fused there.

typedef __attribute__((ext_vector_type(8))) __bf16 bf16x8;
typedef __attribute__((ext_vector_type(16))) float f32x16;
typedef __attribute__((ext_vector_type(4))) float f32x4;

// ws layout (total 7,208,960 B — proven footprint)
#define QKV_OFF   0u         // [256][2368] f32 : q|k|v|pv
#define ARENA_OFF 2424832u   // 2304 B-frags x 1KB bf16 (Wip), frag = n32*48 + k16
#define SC_OFF    4784128u   // [2][12][128][128] f32 (probs after fusion)
#define CTX_OFF   6356992u   // [256][832] f32

// ---------------- fused prep+proj (independent work, one launch) ----------------
// blocks 0..575: prep — Wip [768][1536] f32 -> bf16 B-frags
// blocks 576..723: proj — 4 waves = 4 m-tiles of the wave-block MFMA GEMM
__global__ __launch_bounds__(256)
void prep_proj_kernel(const float* __restrict__ Wip, __bf16* __restrict__ arena,
                      const float* __restrict__ hs,
                      const float* __restrict__ Wq, const float* __restrict__ bq,
                      const float* __restrict__ Wk, const float* __restrict__ bk,
                      const float* __restrict__ Wv, const float* __restrict__ bv,
                      const float* __restrict__ Wpv, const float* __restrict__ bpv,
                      float* __restrict__ qkv) {
  if (blockIdx.x < 576) {
    // ---- prep: frag f = n32*48 + k16 ; lane l: col = n32*32+(l&31), k = k16*16+(l>>5)*8+j
    const int l = threadIdx.x & 63;
    const int f = blockIdx.x * 4 + (threadIdx.x >> 6);   // 0..2303
    const int n32 = f / 48, k16 = f - n32 * 48;
    const float* src = Wip + (size_t)(k16 * 16 + (l >> 5) * 8) * 1536 + n32 * 32 + (l & 31);
    union { __bf16 h[8]; uint4 u; } pk;
#pragma unroll
    for (int j = 0; j < 8; j++) pk.h[j] = (__bf16)src[(size_t)j * 1536];
    ((uint4*)arena)[(size_t)f * 64 + l] = pk.u;
    return;
  }
  // ---- proj: pblk -> (n-tile, m-quad); wave = m-tile within quad
  const int pblk = blockIdx.x - 576;                     // 0..147
  const int n0 = (pblk % 74) * 32;                       // combined col space 2368
  const int m0 = (pblk / 74) * 128 + (threadIdx.x >> 6) * 32;
  const float* W; const float* bias; int noff, ldw;
  if (n0 < 768)       { W = Wq;  bias = bq;  noff = n0;        ldw = 768; }
  else if (n0 < 1536) { W = Wk;  bias = bk;  noff = n0 - 768;  ldw = 768; }
  else if (n0 < 2304) { W = Wv;  bias = bv;  noff = n0 - 1536; ldw = 768; }
  else                { W = Wpv; bias = bpv; noff = n0 - 2304; ldw = 64;  }
  const int l = threadIdx.x & 63;
  const int rsel = l & 31, ksel = l >> 5;
  f32x16 acc;
#pragma unroll
  for (int z = 0; z < 16; z++) acc[z] = 0.f;

#pragma unroll 4
  for (int k16 = 0; k16 < 48; k16++) {
    const float* ap = hs + (size_t)(m0 + rsel) * 768 + k16 * 16 + ksel * 8;
    float4 a0 = *(const float4*)ap;
    float4 a1 = *(const float4*)(ap + 4);
    union { __bf16 h[8]; bf16x8 v; } pa;
    pa.h[0] = (__bf16)a0.x; pa.h[1] = (__bf16)a0.y; pa.h[2] = (__bf16)a0.z; pa.h[3] = (__bf16)a0.w;
    pa.h[4] = (__bf16)a1.x; pa.h[5] = (__bf16)a1.y; pa.h[6] = (__bf16)a1.z; pa.h[7] = (__bf16)a1.w;
    const float* bp = W + (size_t)(k16 * 16 + ksel * 8) * ldw + noff + rsel;
    union { __bf16 h[8]; bf16x8 v; } pb;
#pragma unroll
    for (int j = 0; j < 8; j++) pb.h[j] = (__bf16)bp[(size_t)j * ldw];
    acc = __builtin_amdgcn_mfma_f32_32x32x16_bf16(pa.v, pb.v, acc, 0, 0, 0);
  }
#pragma unroll
  for (int reg = 0; reg < 16; reg++) {
    int row = (reg & 3) + ((reg >> 2) << 3) + (ksel << 2);
    qkv[(size_t)(m0 + row) * 2368 + n0 + rsel] = acc[reg] + bias[noff + rsel];
  }
}

// ---------------- score: fused ip-GEMM + score reduction + SOFTMAX ----------------
// Core FROZEN (R2-proven). New tail: the block's lds_sc[768] is 6 complete
// (h,i) rows -> apply *0.125 + mask + softmax here, write PROBS.
extern __shared__ char smem_raw[];

__global__ __launch_bounds__(512, 2)
void score_kernel(const float* __restrict__ infp,
                  const __bf16* __restrict__ arena,
                  const float* __restrict__ qkv,
                  const float* __restrict__ mask,
                  float* __restrict__ probs) {
  char* Abase = smem_raw;                        // 96 frags * 1040 = 99840 B
  float* lds_sc = (float*)(smem_raw + 99840);    // 64*12 floats
  const int tid = threadIdx.x;
  const int lane = tid & 63;
  const int ml = lane & 31;
  const int kh = lane >> 5;
  const int wv = tid >> 6;
  const int wc = wv & 3;
  const int wd = wv >> 2;
  const int blk = blockIdx.x;
  const int b = blk >> 8;
  const int r0 = (blk & 255) << 6;

  for (int z = tid; z < 768; z += 512) lds_sc[z] = 0.f;

  const uint4* BA = (const uint4*)arena;
  const uint4* bptr  = BA + (size_t)((2 * wc + wd) * 48) * 64 + lane;
  const uint4* bptr2 = bptr + 73728;
  int kpn = 0;                                   // kc the pointer targets
  uint4 B0[8], B1[8], B2[8];
  bf16x8 Af[8];
  f32x16 acc_ra[2], acc_rb[2];

  auto loadB = [&](uint4* dst) {
#pragma unroll
    for (int ks = 0; ks < 4; ks++) {
      dst[ks * 2]     = bptr[ks * 64];           // ra (cols < 768)
      dst[ks * 2 + 1] = bptr2[ks * 64];          // rb (+1152 frags)
    }
    if (kpn == 11) { bptr += 21760; bptr2 += 21760; kpn = 0; }
    else           { bptr += 256;   bptr2 += 256;   kpn++;  }
  };

  // prefetch B for slots 0 and 1: overlaps the HBM A-staging below
  loadB(B0);
  loadB(B1);

  // stage A: 64 rows x 768 f32 -> bf16 frag-ordered LDS (HBM read-once, nt)
  {
    const f32x4* A4 = (const f32x4*)(infp + (size_t)(b * 16384 + r0) * 768);
#pragma unroll
    for (int p = 0; p < 12; p++) {
      int idx = p * 512 + tid;
      int m = (int)(((unsigned)idx * 10923u) >> 20);   // idx/96
      int g = idx - m * 96;
      f32x4 v0 = __builtin_nontemporal_load(A4 + m * 192 + g * 2);
      f32x4 v1 = __builtin_nontemporal_load(A4 + m * 192 + g * 2 + 1);
      union { __bf16 h[8]; uint4 u; } pk;
      pk.h[0] = (__bf16)v0[0]; pk.h[1] = (__bf16)v0[1];
      pk.h[2] = (__bf16)v0[2]; pk.h[3] = (__bf16)v0[3];
      pk.h[4] = (__bf16)v1[0]; pk.h[5] = (__bf16)v1[1];
      pk.h[6] = (__bf16)v1[2]; pk.h[7] = (__bf16)v1[3];
      int F = (m >> 5) * 48 + (g >> 1);
      int slot = (m & 31) + ((g & 1) << 5);
      *(uint4*)(Abase + ((F * 65 + slot) << 4)) = pk.u;
    }
  }
  __syncthreads();

  const size_t lane_off = (size_t)(lane << 4);
  auto loadA = [&](int kcc) {
    const char* ab = Abase + lane_off + kcc * 4160;
#pragma unroll
    for (int mt = 0; mt < 2; mt++)
#pragma unroll
      for (int ks = 0; ks < 4; ks++)
        Af[mt * 4 + ks] = *(const bf16x8*)(ab + mt * 49920 + ks * 1040);
  };
  auto mfma_step = [&](const uint4* Bb) {
#pragma unroll
    for (int ks = 0; ks < 4; ks++) {
      bf16x8 bra = __builtin_bit_cast(bf16x8, Bb[ks * 2]);
      bf16x8 brb = __builtin_bit_cast(bf16x8, Bb[ks * 2 + 1]);
#pragma unroll
      for (int mt = 0; mt < 2; mt++) {
        acc_ra[mt] = __builtin_amdgcn_mfma_f32_32x32x16_bf16(Af[mt * 4 + ks], bra, acc_ra[mt], 0, 0, 0);
        acc_rb[mt] = __builtin_amdgcn_mfma_f32_32x32x16_bf16(Af[mt * 4 + ks], brb, acc_rb[mt], 0, 0, 0);
      }
    }
  };
  auto epilogue = [&](int c) {
    int d = wd * 32 + ml;
#pragma unroll
    for (int mt = 0; mt < 2; mt++) {
      float qv[16], kv[16];
#pragma unroll
      for (int reg = 0; reg < 16; reg++) {
        int row = mt * 32 + (reg & 3) + ((reg >> 2) << 3) + (kh << 2);
        int t = 12 * (r0 + row) + c;
        int hh = t >> 14;
        int ii = (t >> 7) & 127;
        int jj = t & 127;
        qv[reg] = qkv[(size_t)((b << 7) + ii) * 2368 + (hh << 6) + d];
        kv[reg] = qkv[(size_t)((b << 7) + jj) * 2368 + 768 + (hh << 6) + d];
      }
#pragma unroll
      for (int reg = 0; reg < 16; reg++) {
        int row = mt * 32 + (reg & 3) + ((reg >> 2) << 3) + (kh << 2);
        float p = (qv[reg] + acc_ra[mt][reg]) * (kv[reg] + acc_rb[mt][reg]);
        p += __shfl_xor(p, 16);
        p += __shfl_xor(p, 8);
        p += __shfl_xor(p, 4);
        p += __shfl_xor(p, 2);
        p += __shfl_xor(p, 1);
        if (ml == 0) atomicAdd(&lds_sc[row * 12 + c], p);
      }
    }
#pragma unroll
    for (int mt = 0; mt < 2; mt++)
#pragma unroll
      for (int z = 0; z < 16; z++) { acc_ra[mt][z] = 0.f; acc_rb[mt][z] = 0.f; }
  };

#pragma unroll
  for (int mt = 0; mt < 2; mt++)
#pragma unroll
    for (int z = 0; z < 16; z++) { acc_ra[mt][z] = 0.f; acc_rb[mt][z] = 0.f; }

  // 36 slots = 12 iters x 3, banks rotate statically: consume B0,B1,B2 ;
  // slot t prefetches slot t+2's frags into the bank freed at t-1.
  int kcc = 0, cc = wc;
#pragma unroll 1
  for (int it = 0; it < 12; it++) {
    {  // slot 3it+0 : consume B0, prefetch slot 3it+2 -> B2
      loadB(B2);
      loadA(kcc);
      mfma_step(B0);
      if (kcc == 11) { epilogue(cc); kcc = 0; cc += 4; } else kcc++;
    }
    {  // slot 3it+1 : consume B1, prefetch slot 3it+3 -> B0
      if (it < 11) loadB(B0);
      loadA(kcc);
      mfma_step(B1);
      if (kcc == 11) { epilogue(cc); kcc = 0; cc += 4; } else kcc++;
    }
    {  // slot 3it+2 : consume B2, prefetch slot 3it+4 -> B1
      if (it < 11) loadB(B1);
      loadA(kcc);
      mfma_step(B2);
      if (kcc == 11) { epilogue(cc); kcc = 0; cc += 4; } else kcc++;
    }
  }

  __syncthreads();
  // fused softmax tail: lds_sc flat z == t-offset (t = 12*r0 + z) -> 6 full rows.
  // wave rr (0..5) handles row rr: lanes hold j = lane and j = lane+64.
  if (wv < 6) {
    const int z0 = wv << 7;
    float s0 = lds_sc[z0 + lane] * 0.125f + mask[b * 128 + lane];
    float s1 = lds_sc[z0 + lane + 64] * 0.125f + mask[b * 128 + lane + 64];
    float mx = fmaxf(s0, s1);
#pragma unroll
    for (int o = 32; o; o >>= 1) mx = fmaxf(mx, __shfl_xor(mx, o));
    float e0 = __expf(s0 - mx), e1 = __expf(s1 - mx);
    float sm = e0 + e1;
#pragma unroll
    for (int o = 32; o; o >>= 1) sm += __shfl_xor(sm, o);
    float inv = 1.f / sm;
    const int t0 = 12 * r0 + z0;
    const int hh = t0 >> 14;
    const int ii = (t0 >> 7) & 127;
    float* dst = probs + (size_t)((b * 12 + hh) * 128 + ii) * 128;
    dst[lane] = e0 * inv;
    dst[lane + 64] = e1 * inv;
  }
}

// ---------------- attn: pure PV (softmax fused into score) ----------------
// one (b,i) per block; stage 13 weight rows (probs / span) into LDS, then
// float4-vectorized PV: 208 threads, h = tid>>4, d4 = (tid&15)*4.
__global__ __launch_bounds__(256)
void attn_kernel(const float* __restrict__ probs, const float* __restrict__ qkv,
                 const float* __restrict__ span, float* __restrict__ ctx) {
  const int i = blockIdx.x;
  const int b = blockIdx.y;
  const int tid = threadIdx.x;
  const int l = tid & 63;
  const int wvi = tid >> 6;
  __shared__ float w[13][132];
  for (int r = wvi; r < 13; r += 4) {
    const float* sp = (r < 12)
        ? probs + (size_t)((b * 12 + r) * 128 + i) * 128
        : span + (size_t)(b * 128 + i) * 128;
    w[r][l] = sp[l];
    w[r][l + 64] = sp[l + 64];
  }
  __syncthreads();
  if (tid < 208) {
    const int h = tid >> 4;
    const int d4 = (tid & 15) << 2;
    const float* vp = qkv + (size_t)(b * 128) * 2368 + (h < 12 ? 1536 + h * 64 : 2304) + d4;
    f32x4 acc = {0.f, 0.f, 0.f, 0.f};
#pragma unroll 8
    for (int j = 0; j < 128; j++) {
      f32x4 v = *(const f32x4*)(vp + (size_t)j * 2368);
      float ww = w[h][j];
      acc[0] += ww * v[0]; acc[1] += ww * v[1];
      acc[2] += ww * v[2]; acc[3] += ww * v[3];
    }
    *(f32x4*)(ctx + (size_t)(b * 128 + i) * 832 + (h < 12 ? h * 64 : 768) + d4) = acc;
  }
}

// ---------------- out v2: (24 n-tiles, 2 m-supers) x 256 thr (4 waves = 4 m-tiles) ----------------
// 4 waves share the Wmlp fragment stream (L1 hits).
__global__ __launch_bounds__(256)
void out_kernel(const float* __restrict__ ctxb, const float* __restrict__ Wmlp,
                const float* __restrict__ bmlp, float* __restrict__ out) {
  const int n0 = blockIdx.x * 32;
  const int m0 = blockIdx.y * 128 + (threadIdx.x >> 6) * 32;
  const int l = threadIdx.x & 63;
  const int rsel = l & 31, ksel = l >> 5;
  f32x16 acc;
#pragma unroll
  for (int z = 0; z < 16; z++) acc[z] = 0.f;

#pragma unroll 4
  for (int k16 = 0; k16 < 52; k16++) {
    const float* ap = ctxb + (size_t)(m0 + rsel) * 832 + k16 * 16 + ksel * 8;
    float4 a0 = *(const float4*)ap;
    float4 a1 = *(const float4*)(ap + 4);
    union { __bf16 h[8]; bf16x8 v; } pa;
    pa.h[0] = (__bf16)a0.x; pa.h[1] = (__bf16)a0.y; pa.h[2] = (__bf16)a0.z; pa.h[3] = (__bf16)a0.w;
    pa.h[4] = (__bf16)a1.x; pa.h[5] = (__bf16)a1.y; pa.h[6] = (__bf16)a1.z; pa.h[7] = (__bf16)a1.w;
    const float* bp = Wmlp + (size_t)(k16 * 16 + ksel * 8) * 768 + n0 + rsel;
    union { __bf16 h[8]; bf16x8 v; } pb;
#pragma unroll
    for (int j = 0; j < 8; j++) pb.h[j] = (__bf16)bp[(size_t)j * 768];
    acc = __builtin_amdgcn_mfma_f32_32x32x16_bf16(pa.v, pb.v, acc, 0, 0, 0);
  }
#pragma unroll
  for (int reg = 0; reg < 16; reg++) {
    int row = (reg & 3) + ((reg >> 2) << 3) + (ksel << 2);
    out[(size_t)(m0 + row) * 768 + n0 + rsel] = acc[reg] + bmlp[n0 + rsel];
  }
}

// ---------------- launch ----------------
extern "C" void kernel_launch(void* const* d_in, const int* in_sizes, int n_in,
                              void* d_out, int out_size, void* d_ws, size_t ws_size,
                              hipStream_t stream) {
  const float* hs   = (const float*)d_in[0];
  const float* mask = (const float*)d_in[1];
  const float* infp = (const float*)d_in[2];
  const float* span = (const float*)d_in[3];
  const float* Wq   = (const float*)d_in[4];
  const float* bq   = (const float*)d_in[5];
  const float* Wk   = (const float*)d_in[6];
  const float* bk   = (const float*)d_in[7];
  const float* Wv   = (const float*)d_in[8];
  const float* bv   = (const float*)d_in[9];
  const float* Wpv  = (const float*)d_in[10];
  const float* bpv  = (const float*)d_in[11];
  const float* Wip  = (const float*)d_in[12];
  const float* Wmlp = (const float*)d_in[13];
  const float* bmlp = (const float*)d_in[14];
  float* out = (float*)d_out;

  char* ws = (char*)d_ws;
  float*  qkv    = (float*)(ws + QKV_OFF);
  __bf16* arena  = (__bf16*)(ws + ARENA_OFF);
  float*  probs  = (float*)(ws + SC_OFF);
  float*  ctx    = (float*)(ws + CTX_OFF);

  prep_proj_kernel<<<dim3(724), 256, 0, stream>>>(Wip, arena, hs,
      Wq, bq, Wk, bk, Wv, bv, Wpv, bpv, qkv);
  score_kernel<<<dim3(512), 512, 102912, stream>>>(infp, arena, qkv, mask, probs);
  attn_kernel<<<dim3(128, 2), 256, 0, stream>>>(probs, qkv, span, ctx);
  out_kernel<<<dim3(24, 2), 256, 0, stream>>>(ctx, Wmlp, bmlp, out);
}